// Round 15
// baseline (144.871 us; speedup 1.0000x reference)
//
#include <hip/hip_runtime.h>
#include <math.h>

#define TSTEPS 128
#define NFEAT 16
#define NELEM 16   // batch elements per wave

typedef __fp16 f16;
typedef __fp16 f16x2 __attribute__((ext_vector_type(2)));
typedef __fp16 f16x8 __attribute__((ext_vector_type(8)));
typedef float f32x4 __attribute__((ext_vector_type(4)));

union F8 { f16x8 v; f16x2 h[4]; };

__device__ __forceinline__ float frcp(float x){ return __builtin_amdgcn_rcpf(x); }
__device__ __forceinline__ float frsq(float x){ return __builtin_amdgcn_rsqf(x); }
__device__ __forceinline__ float bperm(int addr, float v){
    return __int_as_float(__builtin_amdgcn_ds_bpermute(addr, __float_as_int(v)));
}
__device__ __forceinline__ f16x2 pkrtz(float a, float b){
    return __builtin_amdgcn_cvt_pkrtz(a, b);
}
__device__ __forceinline__ float swz16(float v){   // lane ^= 16 within 32-lane halves
    return __int_as_float(__builtin_amdgcn_ds_swizzle(__float_as_int(v), 0x401F));
}
__device__ __forceinline__ float dpp_xor1(float v){
    return __int_as_float(__builtin_amdgcn_update_dpp(0, __float_as_int(v), 0xB1, 0xF, 0xF, true));
}
__device__ __forceinline__ float dpp_xor2(float v){
    return __int_as_float(__builtin_amdgcn_update_dpp(0, __float_as_int(v), 0x4E, 0xF, 0xF, true));
}
__device__ __forceinline__ float swz_xor4(float v){
    return __int_as_float(__builtin_amdgcn_ds_swizzle(__float_as_int(v), 0x101F));
}
__device__ __forceinline__ float swz_xor8(float v){
    return __int_as_float(__builtin_amdgcn_ds_swizzle(__float_as_int(v), 0x201F));
}
template<int MASK> __device__ __forceinline__ float pshfl(float v){
    if constexpr (MASK == 1) return dpp_xor1(v);
    else if constexpr (MASK == 2) return dpp_xor2(v);
    else if constexpr (MASK == 4) return swz_xor4(v);
    else return swz_xor8(v);
}

__device__ __forceinline__ float sigm(float x){ return frcp(1.f + __expf(-x)); }
__device__ __forceinline__ float tanh_f(float x){ return 1.f - 2.f * frcp(__expf(2.f*x) + 1.f); }

// c = cos(atan(u)/2), s = sin(atan(u)/2)
__device__ __forceinline__ void half_cs(float u, float &c, float &s){
    float ca = frsq(1.f + u*u);
    float x  = (1.f + ca) * 0.5f;
    float t  = frsq(x);
    c = x * t;
    s = u * ca * 0.5f * t;
}

// merged RZ*RY*RX on wire I (prologue / U-construction only)
template<int I>
__device__ __forceinline__ void gate_step(float &re, float &im,
                                          const float* gt, int ai, int loff){
    const float4 g = *(const float4*)((const char*)gt + ai + loff);
    float pre = pshfl<(1 << I)>(re);
    float pim = pshfl<(1 << I)>(im);
    float nre = g.x*re - g.y*im + g.z*pre - g.w*pim;
    float nim = g.x*im + g.y*re + g.z*pim + g.w*pre;
    re = nre; im = nim;
}

// Register-only psi build (no LDS state): 2-stage shuffle butterfly.
// Lane (e,s) holds its wire's half-angle cos/sin; returns B-fragment amps 4s..4s+3.
// amp bits: wire0=j&1, wire1=j>>1, wire2=s&1, wire3=s>>1.
__device__ __forceinline__ F8 psi_butterfly(float c1, float s1, float c2, float s2,
                                            bool odd, bool hihalf, bool sb0, int addr32){
    // own wire factors F(0), F(1)
    float f0r = c1*c2, f0i = -(c1*s2);
    float f1r = s1*c2, f1i = s1*s2;
    // stage 1: xor-16 partner factors (register shuffle, no LDS write)
    float p0r = swz16(f0r), p0i = swz16(f0i);
    float p1r = swz16(f1r), p1i = swz16(f1i);
    // normalize wire order within the pair: lo = even wire (0 or 2), hi = odd wire (1 or 3)
    float lo0r = odd ? p0r : f0r, lo0i = odd ? p0i : f0i;
    float lo1r = odd ? p1r : f1r, lo1i = odd ? p1i : f1i;
    float hi0r = odd ? f0r : p0r, hi0i = odd ? f0i : p0i;
    float hi1r = odd ? f1r : p1r, hi1i = odd ? f1i : p1i;
    // pair products T_j = lo(j&1) * hi(j>>1)
    float T0r = lo0r*hi0r - lo0i*hi0i, T0i = lo0r*hi0i + lo0i*hi0r;
    float T1r = lo1r*hi0r - lo1i*hi0i, T1i = lo1r*hi0i + lo1i*hi0r;
    float T2r = lo0r*hi1r - lo0i*hi1i, T2i = lo0r*hi1i + lo0i*hi1r;
    float T3r = lo1r*hi1r - lo1i*hi1i, T3i = lo1r*hi1i + lo1i*hi1r;
    // stage 2: xor-32 exchange of the T-set (register shuffle via bpermute)
    float R0r = bperm(addr32, T0r), R0i = bperm(addr32, T0i);
    float R1r = bperm(addr32, T1r), R1i = bperm(addr32, T1i);
    float R2r = bperm(addr32, T2r), R2i = bperm(addr32, T2i);
    float R3r = bperm(addr32, T3r), R3i = bperm(addr32, T3i);
    // prefix = (wire2,wire3 set)[s] : hi lanes own T2/T3, lo lanes received R0/R1
    float prr = hihalf ? (sb0 ? T3r : T2r) : (sb0 ? R1r : R0r);
    float pri = hihalf ? (sb0 ? T3i : T2i) : (sb0 ? R1i : R0i);
    // amps' (wire0,wire1) T-set: lo lanes own, hi lanes received
    float A0r = hihalf ? R0r : T0r, A0i = hihalf ? R0i : T0i;
    float A1r = hihalf ? R1r : T1r, A1i = hihalf ? R1i : T1i;
    float A2r = hihalf ? R2r : T2r, A2i = hihalf ? R2i : T2i;
    float A3r = hihalf ? R3r : T3r, A3i = hihalf ? R3i : T3i;
    F8 bp;
    bp.h[0] = pkrtz(A0r*prr - A0i*pri, A0r*pri + A0i*prr);
    bp.h[1] = pkrtz(A1r*prr - A1i*pri, A1r*pri + A1i*prr);
    bp.h[2] = pkrtz(A2r*prr - A2i*pri, A2r*pri + A2i*prr);
    bp.h[3] = pkrtz(A3r*prr - A3i*pri, A3r*pri + A3i*prr);
    return bp;
}

// pack two circuits' probabilities: slot 8s+u: u<4 -> even amp 4s+u, u>=4 -> odd amp 4s+u-4
__device__ __forceinline__ F8 pack_P(const f32x4 &reE, const f32x4 &imE,
                                     const f32x4 &reO, const f32x4 &imO){
    F8 b;
    b.h[0] = pkrtz(reE[0]*reE[0] + imE[0]*imE[0], reE[1]*reE[1] + imE[1]*imE[1]);
    b.h[1] = pkrtz(reE[2]*reE[2] + imE[2]*imE[2], reE[3]*reE[3] + imE[3]*imE[3]);
    b.h[2] = pkrtz(reO[0]*reO[0] + imO[0]*imO[0], reO[1]*reO[1] + imO[1]*imO[1]);
    b.h[3] = pkrtz(reO[2]*reO[2] + imO[2]*imO[2], reO[3]*reO[3] + imO[3]*imO[3]);
    return b;
}

__device__ __forceinline__ float sel4(float a0, float a1, float a2, float a3, int s){
    float lo = (s & 1) ? a1 : a0;
    float hi = (s & 1) ? a3 : a2;
    return (s & 2) ? hi : lo;
}

__global__ void __launch_bounds__(64, 1) qlstm_kernel(
    const float* __restrict__ x, const float* __restrict__ phi,
    const float* __restrict__ Wd, const float* __restrict__ bd,
    float* __restrict__ out, int B)
{
    // gtab: 8 rows (l,i) x 48 floats (12 entries x {Ar,Ai,Br,Bi}) -- 192B stride
    __shared__ __align__(16) float gtab[384];
    __shared__ __align__(16) float ldsf[3072];   // U[k][m][c] complex at k*512+m*32+c*2

    const int tid  = threadIdx.x;
    const int lane = tid & 63;
    const int m    = lane & 15;
    const int grp  = lane >> 4;

    // ---------------- prologue: merged-gate table ----------------------------
    for (int idx = tid; idx < 96; idx += 64){
        int i = idx & 3, l = (idx >> 2) & 1, bb = (idx >> 3) & 1, k = idx >> 4;
        const float* pp = phi + (k*2 + l)*12 + 3*i;
        float ca, sa, cb, sb, cg, sg;
        __sincosf(0.5f*pp[0], &sa, &ca);
        __sincosf(0.5f*pp[1], &sb, &cb);
        __sincosf(0.5f*pp[2], &sg, &cg);
        float Ar, Ai, Br, Bi;
        if (bb == 0){
            float m00r = cb*ca,  m00i = sb*sa;
            float m01r = -sb*ca, m01i = -cb*sa;
            Ar = m00r*cg + m00i*sg;  Ai = m00i*cg - m00r*sg;
            Br = m01r*cg + m01i*sg;  Bi = m01i*cg - m01r*sg;
        } else {
            float m10r = sb*ca, m10i = -cb*sa;
            float m11r = cb*ca, m11i = -sb*sa;
            Ar = m11r*cg - m11i*sg;  Ai = m11i*cg + m11r*sg;
            Br = m10r*cg - m10i*sg;  Bi = m10i*cg + m10r*sg;
        }
        float* dst = gtab + (l*4 + i)*48 + (k*2 + bb)*4;
        dst[0] = Ar; dst[1] = Ai; dst[2] = Br; dst[3] = Bi;
    }
    __syncthreads();

    // CNOT-block permutation P^{-1}(m) and mid-circuit bpermute address
    const int n0 = m & 1, n1 = (m >> 1) & 1, n2 = (m >> 2) & 1, n3 = (m >> 3) & 1;
    const int pm = (n0^n1^n2) | ((n0^n2^n3) << 1) | ((n0^n1^n3) << 2) | ((n0^n1) << 3);
    const int bpaddr = ((lane & 48) | pm) * 4;

    // ---------------- prologue: build U_k columns via shuffle circuit --------
    for (int k = 0; k < 6; ++k){
        int ga0 = 0*192 + k*32 + ((m >> 0) & 1)*16;
        int ga1 = 1*192 + k*32 + ((m >> 1) & 1)*16;
        int ga2 = 2*192 + k*32 + ((m >> 2) & 1)*16;
        int ga3 = 3*192 + k*32 + ((m >> 3) & 1)*16;
        for (int cb = 0; cb < 4; ++cb){
            int c = cb*4 + grp;
            float re = (pm == c) ? 1.f : 0.f;   // P folded into columns
            float im = 0.f;
            gate_step<0>(re, im, gtab, ga0, 0);   gate_step<1>(re, im, gtab, ga1, 0);
            gate_step<2>(re, im, gtab, ga2, 0);   gate_step<3>(re, im, gtab, ga3, 0);
            re = bperm(bpaddr, re);
            im = bperm(bpaddr, im);
            gate_step<0>(re, im, gtab, ga0, 768); gate_step<1>(re, im, gtab, ga1, 768);
            gate_step<2>(re, im, gtab, ga2, 768); gate_step<3>(re, im, gtab, ga3, 768);
            float2* dst = (float2*)&ldsf[k*512 + m*32 + c*2];
            *dst = make_float2(re, im);
        }
    }
    __syncthreads();

    // ---------------- main layout: lane = (e, s) -----------------------------
    const int e = lane & 15;       // batch element (A row, B/D col)
    const int s = lane >> 4;       // own wire / k-quarter
    const bool odd = (s & 1) != 0;
    const bool hihalf = (s & 2) != 0;
    const bool sb0 = odd;
    const int addr32 = (lane ^ 32) * 4;
    const int ecol = e & 3;

    // A-fragments of U_k (re/im)
    F8 are[6], aim[6];
    #pragma unroll
    for (int k = 0; k < 6; ++k){
        const float* ub = &ldsf[k*512 + e*32 + s*8];
        float4 u01 = *(const float4*)ub;         // amps 4s, 4s+1 (re,im)
        float4 u23 = *(const float4*)(ub + 4);   // amps 4s+2, 4s+3
        are[k].h[0] = (f16x2){(f16)u01.x, (f16)(-u01.y)};
        are[k].h[1] = (f16x2){(f16)u01.z, (f16)(-u01.w)};
        are[k].h[2] = (f16x2){(f16)u23.x, (f16)(-u23.y)};
        are[k].h[3] = (f16x2){(f16)u23.z, (f16)(-u23.w)};
        aim[k].h[0] = (f16x2){(f16)u01.y, (f16)u01.x};
        aim[k].h[1] = (f16x2){(f16)u01.w, (f16)u01.z};
        aim[k].h[2] = (f16x2){(f16)u23.y, (f16)u23.x};
        aim[k].h[3] = (f16x2){(f16)u23.w, (f16)u23.z};
    }

    // R8-style packed sign fragment: lane (e,s) output regs 0,1 = ev_s(even ckt), 2,3 = ev_s(odd)
    F8 asig;
    {
        int q = e >> 2;
        bool evenrows = (e & 3) < 2;
        #pragma unroll
        for (int j = 0; j < 8; ++j){
            int amp = 4*s + (j & 3);
            float v = 0.f;
            if (evenrows == (j < 4))
                v = ((amp >> q) & 1) ? -1.f : 1.f;
            asig.v[j] = (f16)v;
        }
    }
    // all-wire sign fragments: evX[j] = ev of wire j (even / odd circuit)
    F8 asigF, asigI;
    #pragma unroll
    for (int u = 0; u < 8; ++u){
        int amp = 4*s + (u & 3);
        float sg = ((amp >> ecol) & 1) ? -1.f : 1.f;
        asigF.v[u] = (f16)(u < 4 ? sg : 0.f);
        asigI.v[u] = (f16)(u >= 4 ? sg : 0.f);
    }

    // A_z (x-only): rows 4q..4q+3 all = Wd column q (k<16) -> dzx[0] = z_x(own wire)
    F8 az;
    #pragma unroll
    for (int j = 0; j < 4; ++j){
        int k0 = s*8 + 2*j, k1 = k0 + 1;
        float v0 = (k0 < 16) ? Wd[k0*20 + (e >> 2)] : 0.f;
        float v1 = (k1 < 16) ? Wd[k1*20 + (e >> 2)] : 0.f;
        az.h[j] = (f16x2){(f16)v0, (f16)v1};
    }
    const float bdv = bd[s];
    // Wd_h column s in f32: z_h,s = sum_q Wd[16+q][s] * h_q
    const float4 wqs = make_float4(Wd[16*20 + s], Wd[17*20 + s],
                                   Wd[18*20 + s], Wd[19*20 + s]);

    const int b0 = blockIdx.x * NELEM;
    const float* xp = x + (size_t)(b0 + e) * TSTEPS * NFEAT;
    float* yp = out + (size_t)(b0 + e) * TSTEPS * 4 + s;

    const f32x4 z4 = {0.f, 0.f, 0.f, 0.f};
    const f16x2 zh = pkrtz(0.f, 0.f);
    float cst = 0.f;
    f32x4 hv = z4;                  // all-wire h state (f32, replicated across s)

    // x prefetch + pipelined z_x MFMA for t=0 (s*8 slot offset!)
    float4 xa = {0,0,0,0}, xb = {0,0,0,0};
    if (s < 2){
        xa = *(const float4*)(xp + s*8);
        xb = *(const float4*)(xp + s*8 + 4);
    }
    F8 bz;
    bz.h[0] = (s < 2) ? pkrtz(xa.x, xa.y) : zh;
    bz.h[1] = (s < 2) ? pkrtz(xa.z, xa.w) : zh;
    bz.h[2] = (s < 2) ? pkrtz(xb.x, xb.y) : zh;
    bz.h[3] = (s < 2) ? pkrtz(xb.z, xb.w) : zh;
    f32x4 dzx = __builtin_amdgcn_mfma_f32_16x16x32_f16(az.v, bz.v, z4, 0, 0, 0);
    if (s < 2){
        xa = *(const float4*)(xp + NFEAT + s*8);
        xb = *(const float4*)(xp + NFEAT + s*8 + 4);
    }

    #pragma clang loop unroll(disable)
    for (int t = 0; t < TSTEPS; ++t){
        // ---- z (own wire) = z_x (pipelined MFMA) + Wd_h^T h (f32 VALU) + bd ----
        float zval = dzx[0] + bdv
                   + wqs.x*hv[0] + wqs.y*hv[1] + wqs.z*hv[2] + wqs.w*hv[3];
        float usel = 1.f - 2.f*frcp(__expf(zval) + 1.f);
        float c1, s1, c2, s2;
        half_cs(usel, c1, s1);
        half_cs(usel*usel, c2, s2);
        F8 bp = psi_butterfly(c1, s1, c2, s2, odd, hihalf, sb0, addr32);

        // ---- phase 1: f,i,Cg,o = 8 U-MFMAs + 2 EV-MFMAs (packed, own wire) ----
        f32x4 dre[4], dim4[4];
        #pragma unroll
        for (int k = 0; k < 4; ++k){
            dre[k]  = __builtin_amdgcn_mfma_f32_16x16x32_f16(are[k].v, bp.v, z4, 0,0,0);
            dim4[k] = __builtin_amdgcn_mfma_f32_16x16x32_f16(aim[k].v, bp.v, z4, 0,0,0);
        }
        F8 pb1 = pack_P(dre[0], dim4[0], dre[1], dim4[1]);   // f (even), i (odd)
        F8 pb2 = pack_P(dre[2], dim4[2], dre[3], dim4[3]);   // Cg, o
        f32x4 ev1 = __builtin_amdgcn_mfma_f32_16x16x32_f16(asig.v, pb1.v, z4, 0,0,0);
        f32x4 ev2 = __builtin_amdgcn_mfma_f32_16x16x32_f16(asig.v, pb2.v, z4, 0,0,0);

        // ---- pipelined z_x for t+1 ----
        if (t + 1 < TSTEPS){
            bz.h[0] = (s < 2) ? pkrtz(xa.x, xa.y) : zh;
            bz.h[1] = (s < 2) ? pkrtz(xa.z, xa.w) : zh;
            bz.h[2] = (s < 2) ? pkrtz(xb.x, xb.y) : zh;
            bz.h[3] = (s < 2) ? pkrtz(xb.z, xb.w) : zh;
            dzx = __builtin_amdgcn_mfma_f32_16x16x32_f16(az.v, bz.v, z4, 0,0,0);
            if (s < 2 && t + 2 < TSTEPS){
                xa = *(const float4*)(xp + (t+2)*NFEAT + s*8);
                xb = *(const float4*)(xp + (t+2)*NFEAT + s*8 + 4);
            }
        }

        // ---- LSTM pointwise (own wire s only) ----
        float fg = sigm(ev1[0]), ig = sigm(ev1[2]), Cg = sigm(ev2[0]), og = sigm(ev2[2]);
        cst = fg*cst + ig*Cg;
        float rs = og * tanh_f(cst);
        half_cs(rs, c1, s1);
        half_cs(rs*rs, c2, s2);
        F8 bpp = psi_butterfly(c1, s1, c2, s2, odd, hihalf, sb0, addr32);

        // ---- phase 2: h (k=4), y (k=5) = 4 U-MFMAs + 2 EV-MFMAs ----
        f32x4 hre = __builtin_amdgcn_mfma_f32_16x16x32_f16(are[4].v, bpp.v, z4, 0,0,0);
        f32x4 him = __builtin_amdgcn_mfma_f32_16x16x32_f16(aim[4].v, bpp.v, z4, 0,0,0);
        f32x4 yre = __builtin_amdgcn_mfma_f32_16x16x32_f16(are[5].v, bpp.v, z4, 0,0,0);
        f32x4 yim = __builtin_amdgcn_mfma_f32_16x16x32_f16(aim[5].v, bpp.v, z4, 0,0,0);
        F8 b3 = pack_P(hre, him, yre, yim);                 // h (even), y (odd)
        hv = __builtin_amdgcn_mfma_f32_16x16x32_f16(asigF.v, b3.v, z4, 0,0,0);  // all-wire h
        f32x4 evY = __builtin_amdgcn_mfma_f32_16x16x32_f16(asigI.v, b3.v, z4, 0,0,0);

        // ---- y scatter (own wire, off critical path) ----
        yp[t*4] = sel4(evY[0], evY[1], evY[2], evY[3], s);
    }

    // final c (own wire), h (select own wire from all-wire state)
    size_t cbase = (size_t)B * TSTEPS * 4;
    out[cbase + (size_t)(b0 + e)*4 + s] = cst;
    out[cbase + (size_t)B*4 + (size_t)(b0 + e)*4 + s] = sel4(hv[0], hv[1], hv[2], hv[3], s);
}

extern "C" void kernel_launch(void* const* d_in, const int* in_sizes, int n_in,
                              void* d_out, int out_size, void* d_ws, size_t ws_size,
                              hipStream_t stream) {
    const float* x   = (const float*)d_in[0];
    const float* phi = (const float*)d_in[1];
    const float* Wd  = (const float*)d_in[2];
    const float* bd  = (const float*)d_in[3];
    float* out = (float*)d_out;
    int B = in_sizes[0] / (TSTEPS * NFEAT);   // 4096
    int blocks = B / NELEM;                   // 256 blocks x 1 wave x 16 elems
    hipLaunchKernelGGL(qlstm_kernel, dim3(blocks), dim3(64), 0, stream,
                       x, phi, Wd, bd, out, B);
}

// Round 16
// 129.038 us; speedup vs baseline: 1.1227x; 1.1227x over previous
//
#include <hip/hip_runtime.h>
#include <math.h>

#define TSTEPS 128
#define NFEAT 16
#define NELEM 16   // batch elements per wave

typedef __fp16 f16;
typedef __fp16 f16x2 __attribute__((ext_vector_type(2)));
typedef __fp16 f16x8 __attribute__((ext_vector_type(8)));
typedef float f32x4 __attribute__((ext_vector_type(4)));

union F8 { f16x8 v; f16x2 h[4]; };

__device__ __forceinline__ float frcp(float x){ return __builtin_amdgcn_rcpf(x); }
__device__ __forceinline__ float frsq(float x){ return __builtin_amdgcn_rsqf(x); }
__device__ __forceinline__ float bperm(int addr, float v){
    return __int_as_float(__builtin_amdgcn_ds_bpermute(addr, __float_as_int(v)));
}
__device__ __forceinline__ f16x2 pkrtz(float a, float b){
    return __builtin_amdgcn_cvt_pkrtz(a, b);
}
__device__ __forceinline__ float dpp_xor1(float v){
    return __int_as_float(__builtin_amdgcn_update_dpp(0, __float_as_int(v), 0xB1, 0xF, 0xF, true));
}
__device__ __forceinline__ float dpp_xor2(float v){
    return __int_as_float(__builtin_amdgcn_update_dpp(0, __float_as_int(v), 0x4E, 0xF, 0xF, true));
}
__device__ __forceinline__ float swz_xor4(float v){
    return __int_as_float(__builtin_amdgcn_ds_swizzle(__float_as_int(v), 0x101F));
}
__device__ __forceinline__ float swz_xor8(float v){
    return __int_as_float(__builtin_amdgcn_ds_swizzle(__float_as_int(v), 0x201F));
}
template<int MASK> __device__ __forceinline__ float pshfl(float v){
    if constexpr (MASK == 1) return dpp_xor1(v);
    else if constexpr (MASK == 2) return dpp_xor2(v);
    else if constexpr (MASK == 4) return swz_xor4(v);
    else return swz_xor8(v);
}
__device__ __forceinline__ void cfence(){ __asm__ __volatile__("" ::: "memory"); }

__device__ __forceinline__ float sigm(float x){ return frcp(1.f + __expf(-x)); }
__device__ __forceinline__ float tanh_f(float x){ return 1.f - 2.f * frcp(__expf(2.f*x) + 1.f); }

// c = cos(atan(u)/2), s = sin(atan(u)/2)
__device__ __forceinline__ void half_cs(float u, float &c, float &s){
    float ca = frsq(1.f + u*u);
    float x  = (1.f + ca) * 0.5f;
    float t  = frsq(x);
    c = x * t;
    s = u * ca * 0.5f * t;
}

// merged RZ*RY*RX on wire I (prologue / U-construction only)
template<int I>
__device__ __forceinline__ void gate_step(float &re, float &im,
                                          const float* gt, int ai, int loff){
    const float4 g = *(const float4*)((const char*)gt + ai + loff);
    float pre = pshfl<(1 << I)>(re);
    float pim = pshfl<(1 << I)>(im);
    float nre = g.x*re - g.y*im + g.z*pre - g.w*pim;
    float nim = g.x*im + g.y*re + g.z*pim + g.w*pre;
    re = nre; im = nim;
}

// lane (e,s) emits complex factors F_s(0), F_s(1) of its wire into LDS
__device__ __forceinline__ void write_F(float* bc, int e, int s,
                                        float c1, float s1, float c2, float s2){
    float4 w;
    w.x = c1 * c2;  w.y = -(c1 * s2);    // F(0)
    w.z = s1 * c2;  w.w = s1 * s2;       // F(1)
    *(float4*)(bc + e*20 + s*4) = w;
}

// lane (e,s) builds its 4 amplitudes a=4s..4s+3 of elem e's init state (B-fragment)
__device__ __forceinline__ void build_psi(const float* bc, int e, int sm1, int sm2,
                                          F8 &bp){
    const float4 w0 = *(const float4*)(bc + e*20);               // wire0: F(0),F(1)
    const float4 w1 = *(const float4*)(bc + e*20 + 4);           // wire1
    const float2 F2 = *(const float2*)(bc + e*20 + 8  + sm1*2);  // F_2(s&1)
    const float2 F3 = *(const float2*)(bc + e*20 + 12 + sm2*2);  // F_3(s>>1)
    float pr = F2.x*F3.x - F2.y*F3.y;
    float pi = F2.x*F3.y + F2.y*F3.x;                            // prefix
    float P0r = pr*w1.x - pi*w1.y, P0i = pr*w1.y + pi*w1.x;      // prefix*F1(0)
    float P1r = pr*w1.z - pi*w1.w, P1i = pr*w1.w + pi*w1.z;      // prefix*F1(1)
    float a0r = P0r*w0.x - P0i*w0.y, a0i = P0r*w0.y + P0i*w0.x;
    float a1r = P0r*w0.z - P0i*w0.w, a1i = P0r*w0.w + P0i*w0.z;
    float a2r = P1r*w0.x - P1i*w0.y, a2i = P1r*w0.y + P1i*w0.x;
    float a3r = P1r*w0.z - P1i*w0.w, a3i = P1r*w0.w + P1i*w0.z;
    bp.h[0] = pkrtz(a0r, a0i);
    bp.h[1] = pkrtz(a1r, a1i);
    bp.h[2] = pkrtz(a2r, a2i);
    bp.h[3] = pkrtz(a3r, a3i);
}

// pack two circuits' probabilities: slot 8s+u: u<4 -> even amp 4s+u, u>=4 -> odd amp 4s+u-4
__device__ __forceinline__ F8 pack_P(const f32x4 &reE, const f32x4 &imE,
                                     const f32x4 &reO, const f32x4 &imO){
    F8 b;
    b.h[0] = pkrtz(reE[0]*reE[0] + imE[0]*imE[0], reE[1]*reE[1] + imE[1]*imE[1]);
    b.h[1] = pkrtz(reE[2]*reE[2] + imE[2]*imE[2], reE[3]*reE[3] + imE[3]*imE[3]);
    b.h[2] = pkrtz(reO[0]*reO[0] + imO[0]*imO[0], reO[1]*reO[1] + imO[1]*imO[1]);
    b.h[3] = pkrtz(reO[2]*reO[2] + imO[2]*imO[2], reO[3]*reO[3] + imO[3]*imO[3]);
    return b;
}

__device__ __forceinline__ float sel4(float a0, float a1, float a2, float a3, int s){
    float lo = (s & 1) ? a1 : a0;
    float hi = (s & 1) ? a3 : a2;
    return (s & 2) ? hi : lo;
}

__global__ void __launch_bounds__(64, 1) qlstm_kernel(
    const float* __restrict__ x, const float* __restrict__ phi,
    const float* __restrict__ Wd, const float* __restrict__ bd,
    float* __restrict__ out, int B)
{
    // gtab: 8 rows (l,i) x 48 floats (12 entries x {Ar,Ai,Br,Bi}) -- 192B stride
    __shared__ __align__(16) float gtab[384];
    __shared__ __align__(16) float ldsf[3072];
    const int UBo = 0;      // 3072 floats: U[k][m][c] complex at k*512+m*32+c*2
    const int BCo = 0;      // factor pairs alias the U region (U read only in prologue)

    const int tid  = threadIdx.x;
    const int lane = tid & 63;
    const int m    = lane & 15;
    const int grp  = lane >> 4;

    // ---------------- prologue: merged-gate table ----------------------------
    for (int idx = tid; idx < 96; idx += 64){
        int i = idx & 3, l = (idx >> 2) & 1, bb = (idx >> 3) & 1, k = idx >> 4;
        const float* pp = phi + (k*2 + l)*12 + 3*i;
        float ca, sa, cb, sb, cg, sg;
        __sincosf(0.5f*pp[0], &sa, &ca);
        __sincosf(0.5f*pp[1], &sb, &cb);
        __sincosf(0.5f*pp[2], &sg, &cg);
        float Ar, Ai, Br, Bi;
        if (bb == 0){
            float m00r = cb*ca,  m00i = sb*sa;
            float m01r = -sb*ca, m01i = -cb*sa;
            Ar = m00r*cg + m00i*sg;  Ai = m00i*cg - m00r*sg;
            Br = m01r*cg + m01i*sg;  Bi = m01i*cg - m01r*sg;
        } else {
            float m10r = sb*ca, m10i = -cb*sa;
            float m11r = cb*ca, m11i = -sb*sa;
            Ar = m11r*cg - m11i*sg;  Ai = m11i*cg + m11r*sg;
            Br = m10r*cg - m10i*sg;  Bi = m10i*cg + m10r*sg;
        }
        float* dst = gtab + (l*4 + i)*48 + (k*2 + bb)*4;
        dst[0] = Ar; dst[1] = Ai; dst[2] = Br; dst[3] = Bi;
    }
    __syncthreads();

    // CNOT-block permutation P^{-1}(m) and mid-circuit bpermute address
    const int n0 = m & 1, n1 = (m >> 1) & 1, n2 = (m >> 2) & 1, n3 = (m >> 3) & 1;
    const int pm = (n0^n1^n2) | ((n0^n2^n3) << 1) | ((n0^n1^n3) << 2) | ((n0^n1) << 3);
    const int bpaddr = ((lane & 48) | pm) * 4;

    // ---------------- prologue: build U_k columns via shuffle circuit --------
    for (int k = 0; k < 6; ++k){
        int ga0 = 0*192 + k*32 + ((m >> 0) & 1)*16;
        int ga1 = 1*192 + k*32 + ((m >> 1) & 1)*16;
        int ga2 = 2*192 + k*32 + ((m >> 2) & 1)*16;
        int ga3 = 3*192 + k*32 + ((m >> 3) & 1)*16;
        for (int cb = 0; cb < 4; ++cb){
            int c = cb*4 + grp;
            float re = (pm == c) ? 1.f : 0.f;   // P folded into columns
            float im = 0.f;
            gate_step<0>(re, im, gtab, ga0, 0);   gate_step<1>(re, im, gtab, ga1, 0);
            gate_step<2>(re, im, gtab, ga2, 0);   gate_step<3>(re, im, gtab, ga3, 0);
            re = bperm(bpaddr, re);
            im = bperm(bpaddr, im);
            gate_step<0>(re, im, gtab, ga0, 768); gate_step<1>(re, im, gtab, ga1, 768);
            gate_step<2>(re, im, gtab, ga2, 768); gate_step<3>(re, im, gtab, ga3, 768);
            float2* dst = (float2*)&ldsf[UBo + k*512 + m*32 + c*2];
            *dst = make_float2(re, im);
        }
    }
    __syncthreads();

    // ---------------- main layout: lane = (e, s) -----------------------------
    const int e = lane & 15;       // batch element (A row, B/D col)
    const int s = lane >> 4;       // own wire / k-quarter
    const int sm1 = s & 1, sm2 = s >> 1;
    const int ecol = e & 3;

    // A-fragments of U_k (re/im) -- loaded once, pinned by the aliasing stores
    F8 are[6], aim[6];
    #pragma unroll
    for (int k = 0; k < 6; ++k){
        const float* ub = &ldsf[UBo + k*512 + e*32 + s*8];
        float4 u01 = *(const float4*)ub;         // amps 4s, 4s+1 (re,im)
        float4 u23 = *(const float4*)(ub + 4);   // amps 4s+2, 4s+3
        are[k].h[0] = (f16x2){(f16)u01.x, (f16)(-u01.y)};
        are[k].h[1] = (f16x2){(f16)u01.z, (f16)(-u01.w)};
        are[k].h[2] = (f16x2){(f16)u23.x, (f16)(-u23.y)};
        are[k].h[3] = (f16x2){(f16)u23.z, (f16)(-u23.w)};
        aim[k].h[0] = (f16x2){(f16)u01.y, (f16)u01.x};
        aim[k].h[1] = (f16x2){(f16)u01.w, (f16)u01.z};
        aim[k].h[2] = (f16x2){(f16)u23.y, (f16)u23.x};
        aim[k].h[3] = (f16x2){(f16)u23.w, (f16)u23.z};
    }
    __syncthreads();   // all lanes done reading U before anyone overwrites it

    // R8-style packed sign fragment: lane (e,s) output regs 0,1 = ev_s(even ckt), 2,3 = ev_s(odd)
    F8 asig;
    {
        int q = e >> 2;
        bool evenrows = (e & 3) < 2;
        #pragma unroll
        for (int j = 0; j < 8; ++j){
            int amp = 4*s + (j & 3);
            float v = 0.f;
            if (evenrows == (j < 4))
                v = ((amp >> q) & 1) ? -1.f : 1.f;
            asig.v[j] = (f16)v;
        }
    }
    // all-wire sign fragments: evX[j] = ev of wire j (even / odd circuit)
    F8 asigF, asigI;
    #pragma unroll
    for (int u = 0; u < 8; ++u){
        int amp = 4*s + (u & 3);
        float sg = ((amp >> ecol) & 1) ? -1.f : 1.f;
        asigF.v[u] = (f16)(u < 4 ? sg : 0.f);
        asigI.v[u] = (f16)(u >= 4 ? sg : 0.f);
    }

    // A_z (x-only): rows 4q..4q+3 all = Wd column q (k<16) -> dzx[0] = z_x(own wire)
    F8 az;
    #pragma unroll
    for (int j = 0; j < 4; ++j){
        int k0 = s*8 + 2*j, k1 = k0 + 1;
        float v0 = (k0 < 16) ? Wd[k0*20 + (e >> 2)] : 0.f;
        float v1 = (k1 < 16) ? Wd[k1*20 + (e >> 2)] : 0.f;
        az.h[j] = (f16x2){(f16)v0, (f16)v1};
    }
    const float bdv = bd[s];
    // Wd_h column s in f32: z_h,s = sum_q Wd[16+q][s] * h_q
    const float4 wqs = make_float4(Wd[16*20 + s], Wd[17*20 + s],
                                   Wd[18*20 + s], Wd[19*20 + s]);

    const int b0 = blockIdx.x * NELEM;
    const float* xp = x + (size_t)(b0 + e) * TSTEPS * NFEAT;
    float* yp = out + (size_t)(b0 + e) * TSTEPS * 4 + s;

    const f32x4 z4 = {0.f, 0.f, 0.f, 0.f};
    const f16x2 zh = pkrtz(0.f, 0.f);
    float cst = 0.f;
    f32x4 hv = z4;                  // all-wire h state (f32, replicated across s)

    // x prefetch + pipelined z_x MFMA for t=0 (s*8 slot offset!)
    float4 xa = {0,0,0,0}, xb = {0,0,0,0};
    if (s < 2){
        xa = *(const float4*)(xp + s*8);
        xb = *(const float4*)(xp + s*8 + 4);
    }
    F8 bz;
    bz.h[0] = (s < 2) ? pkrtz(xa.x, xa.y) : zh;
    bz.h[1] = (s < 2) ? pkrtz(xa.z, xa.w) : zh;
    bz.h[2] = (s < 2) ? pkrtz(xb.x, xb.y) : zh;
    bz.h[3] = (s < 2) ? pkrtz(xb.z, xb.w) : zh;
    f32x4 dzx = __builtin_amdgcn_mfma_f32_16x16x32_f16(az.v, bz.v, z4, 0, 0, 0);
    if (s < 2){
        xa = *(const float4*)(xp + NFEAT + s*8);
        xb = *(const float4*)(xp + NFEAT + s*8 + 4);
    }

    #pragma clang loop unroll(disable)
    for (int t = 0; t < TSTEPS; ++t){
        // ---- z (own wire) = z_x (pipelined MFMA) + Wd_h^T h (f32 VALU) + bd ----
        float zval = dzx[0] + bdv
                   + wqs.x*hv[0] + wqs.y*hv[1] + wqs.z*hv[2] + wqs.w*hv[3];
        float usel = 1.f - 2.f*frcp(__expf(zval) + 1.f);
        float c1, s1, c2, s2;
        half_cs(usel, c1, s1);
        half_cs(usel*usel, c2, s2);
        write_F(&ldsf[BCo], e, s, c1, s1, c2, s2);
        cfence();
        F8 bp;
        build_psi(&ldsf[BCo], e, sm1, sm2, bp);

        // ---- phase 1: f,i,Cg,o = 8 U-MFMAs + 2 EV-MFMAs (packed, own wire) ----
        f32x4 dre[4], dim4[4];
        #pragma unroll
        for (int k = 0; k < 4; ++k){
            dre[k]  = __builtin_amdgcn_mfma_f32_16x16x32_f16(are[k].v, bp.v, z4, 0,0,0);
            dim4[k] = __builtin_amdgcn_mfma_f32_16x16x32_f16(aim[k].v, bp.v, z4, 0,0,0);
        }
        F8 pb1 = pack_P(dre[0], dim4[0], dre[1], dim4[1]);   // f (even), i (odd)
        F8 pb2 = pack_P(dre[2], dim4[2], dre[3], dim4[3]);   // Cg, o
        f32x4 ev1 = __builtin_amdgcn_mfma_f32_16x16x32_f16(asig.v, pb1.v, z4, 0,0,0);
        f32x4 ev2 = __builtin_amdgcn_mfma_f32_16x16x32_f16(asig.v, pb2.v, z4, 0,0,0);

        // ---- pipelined z_x for t+1 ----
        if (t + 1 < TSTEPS){
            bz.h[0] = (s < 2) ? pkrtz(xa.x, xa.y) : zh;
            bz.h[1] = (s < 2) ? pkrtz(xa.z, xa.w) : zh;
            bz.h[2] = (s < 2) ? pkrtz(xb.x, xb.y) : zh;
            bz.h[3] = (s < 2) ? pkrtz(xb.z, xb.w) : zh;
            dzx = __builtin_amdgcn_mfma_f32_16x16x32_f16(az.v, bz.v, z4, 0,0,0);
            if (s < 2 && t + 2 < TSTEPS){
                xa = *(const float4*)(xp + (t+2)*NFEAT + s*8);
                xb = *(const float4*)(xp + (t+2)*NFEAT + s*8 + 4);
            }
        }

        // ---- LSTM pointwise (own wire s only) ----
        float fg = sigm(ev1[0]), ig = sigm(ev1[2]), Cg = sigm(ev2[0]), og = sigm(ev2[2]);
        cst = fg*cst + ig*Cg;
        float rs = og * tanh_f(cst);
        half_cs(rs, c1, s1);
        half_cs(rs*rs, c2, s2);
        write_F(&ldsf[BCo], e, s, c1, s1, c2, s2);
        cfence();
        F8 bpp;
        build_psi(&ldsf[BCo], e, sm1, sm2, bpp);

        // ---- phase 2: h (k=4), y (k=5) = 4 U-MFMAs + 2 EV-MFMAs ----
        f32x4 hre = __builtin_amdgcn_mfma_f32_16x16x32_f16(are[4].v, bpp.v, z4, 0,0,0);
        f32x4 him = __builtin_amdgcn_mfma_f32_16x16x32_f16(aim[4].v, bpp.v, z4, 0,0,0);
        f32x4 yre = __builtin_amdgcn_mfma_f32_16x16x32_f16(are[5].v, bpp.v, z4, 0,0,0);
        f32x4 yim = __builtin_amdgcn_mfma_f32_16x16x32_f16(aim[5].v, bpp.v, z4, 0,0,0);
        F8 b3 = pack_P(hre, him, yre, yim);                 // h (even), y (odd)
        hv = __builtin_amdgcn_mfma_f32_16x16x32_f16(asigF.v, b3.v, z4, 0,0,0);  // all-wire h
        f32x4 evY = __builtin_amdgcn_mfma_f32_16x16x32_f16(asigI.v, b3.v, z4, 0,0,0);

        // ---- y scatter (own wire, off critical path) ----
        yp[t*4] = sel4(evY[0], evY[1], evY[2], evY[3], s);
    }

    // final c (own wire), h (select own wire from all-wire state)
    size_t cbase = (size_t)B * TSTEPS * 4;
    out[cbase + (size_t)(b0 + e)*4 + s] = cst;
    out[cbase + (size_t)B*4 + (size_t)(b0 + e)*4 + s] = sel4(hv[0], hv[1], hv[2], hv[3], s);
}

extern "C" void kernel_launch(void* const* d_in, const int* in_sizes, int n_in,
                              void* d_out, int out_size, void* d_ws, size_t ws_size,
                              hipStream_t stream) {
    const float* x   = (const float*)d_in[0];
    const float* phi = (const float*)d_in[1];
    const float* Wd  = (const float*)d_in[2];
    const float* bd  = (const float*)d_in[3];
    float* out = (float*)d_out;
    int B = in_sizes[0] / (TSTEPS * NFEAT);   // 4096
    int blocks = B / NELEM;                   // 256 blocks x 1 wave x 16 elems
    hipLaunchKernelGGL(qlstm_kernel, dim3(blocks), dim3(64), 0, stream,
                       x, phi, Wd, bd, out, B);
}

// Round 17
// 124.999 us; speedup vs baseline: 1.1590x; 1.0323x over previous
//
#include <hip/hip_runtime.h>
#include <math.h>

#define TSTEPS 128
#define NFEAT 16
#define NELEM 16   // batch elements per wave

typedef __fp16 f16;
typedef __fp16 f16x2 __attribute__((ext_vector_type(2)));
typedef __fp16 f16x8 __attribute__((ext_vector_type(8)));
typedef float f32x4 __attribute__((ext_vector_type(4)));

union F8 { f16x8 v; f16x2 h[4]; };

__device__ __forceinline__ float frcp(float x){ return __builtin_amdgcn_rcpf(x); }
__device__ __forceinline__ float frsq(float x){ return __builtin_amdgcn_rsqf(x); }
__device__ __forceinline__ float bperm(int addr, float v){
    return __int_as_float(__builtin_amdgcn_ds_bpermute(addr, __float_as_int(v)));
}
__device__ __forceinline__ f16x2 pkrtz(float a, float b){
    return __builtin_amdgcn_cvt_pkrtz(a, b);
}
__device__ __forceinline__ float dpp_xor1(float v){
    return __int_as_float(__builtin_amdgcn_update_dpp(0, __float_as_int(v), 0xB1, 0xF, 0xF, true));
}
__device__ __forceinline__ float dpp_xor2(float v){
    return __int_as_float(__builtin_amdgcn_update_dpp(0, __float_as_int(v), 0x4E, 0xF, 0xF, true));
}
__device__ __forceinline__ float swz_xor4(float v){
    return __int_as_float(__builtin_amdgcn_ds_swizzle(__float_as_int(v), 0x101F));
}
__device__ __forceinline__ float swz_xor8(float v){
    return __int_as_float(__builtin_amdgcn_ds_swizzle(__float_as_int(v), 0x201F));
}
template<int MASK> __device__ __forceinline__ float pshfl(float v){
    if constexpr (MASK == 1) return dpp_xor1(v);
    else if constexpr (MASK == 2) return dpp_xor2(v);
    else if constexpr (MASK == 4) return swz_xor4(v);
    else return swz_xor8(v);
}
__device__ __forceinline__ void cfence(){ __asm__ __volatile__("" ::: "memory"); }

__device__ __forceinline__ float sigm(float x){ return frcp(1.f + __expf(-x)); }
__device__ __forceinline__ float tanh_f(float x){ return 1.f - 2.f * frcp(__expf(2.f*x) + 1.f); }

// merged RZ*RY*RX on wire I (prologue / U-construction only)
template<int I>
__device__ __forceinline__ void gate_step(float &re, float &im,
                                          const float* gt, int ai, int loff){
    const float4 g = *(const float4*)((const char*)gt + ai + loff);
    float pre = pshfl<(1 << I)>(re);
    float pim = pshfl<(1 << I)>(im);
    float nre = g.x*re - g.y*im + g.z*pre - g.w*pim;
    float nim = g.x*im + g.y*re + g.z*pim + g.w*pre;
    re = nre; im = nim;
}

// prologue-only half-angle helper
__device__ __forceinline__ void half_cs(float u, float &c, float &s){
    float ca = frsq(1.f + u*u);
    float x  = (1.f + ca) * 0.5f;
    float t  = frsq(x);
    c = x * t;
    s = u * ca * 0.5f * t;
}

// fused factor products: F(0) = (c1c2, -c1s2), F(1) = (s1c2, s1s2)
// for angles atan(u) (RY) and atan(u^2) (RZ) -- 3 trans instead of 4:
// sqrt(x1)*sqrt(x2) = x1*x2*rsq(x1*x2), sqrt(x2)/sqrt(x1) = x2*rsq(x1*x2), etc.
__device__ __forceinline__ void factors(float u, float &F0r, float &F0i,
                                        float &F1r, float &F1i){
    float u2  = u * u;
    float ca1 = frsq(1.f + u2);          // cos(atan u)
    float ca2 = frsq(1.f + u2*u2);       // cos(atan u^2)
    float x1  = (1.f + ca1) * 0.5f;      // cos^2 of half-angles
    float x2  = (1.f + ca2) * 0.5f;
    float x12 = x1 * x2;
    float t   = frsq(x12);
    float a1  = u  * ca1 * 0.5f;         // sin1 * c1 (i.e. s1*c1... = sin/2)
    float a2  = u2 * ca2 * 0.5f;
    F0r = x12 * t;                       // c1*c2
    F0i = -(a2 * x1 * t);                // -(c1*s2)
    F1r = a1 * x2 * t;                   // s1*c2
    F1i = a1 * a2 * t;                   // s1*s2
}

// lane (e,s) emits complex factors F_s(0), F_s(1) of its wire into LDS
__device__ __forceinline__ void write_F(float* bc, int e, int s,
                                        float F0r, float F0i, float F1r, float F1i){
    float4 w;
    w.x = F0r; w.y = F0i; w.z = F1r; w.w = F1i;
    *(float4*)(bc + e*20 + s*4) = w;
}

// lane (e,s) builds its 4 amplitudes a=4s..4s+3 of elem e's init state (B-fragment)
__device__ __forceinline__ void build_psi(const float* bc, int e, int sm1, int sm2,
                                          F8 &bp){
    const float4 w0 = *(const float4*)(bc + e*20);               // wire0: F(0),F(1)
    const float4 w1 = *(const float4*)(bc + e*20 + 4);           // wire1
    const float2 F2 = *(const float2*)(bc + e*20 + 8  + sm1*2);  // F_2(s&1)
    const float2 F3 = *(const float2*)(bc + e*20 + 12 + sm2*2);  // F_3(s>>1)
    float pr = F2.x*F3.x - F2.y*F3.y;
    float pi = F2.x*F3.y + F2.y*F3.x;                            // prefix
    float P0r = pr*w1.x - pi*w1.y, P0i = pr*w1.y + pi*w1.x;      // prefix*F1(0)
    float P1r = pr*w1.z - pi*w1.w, P1i = pr*w1.w + pi*w1.z;      // prefix*F1(1)
    float a0r = P0r*w0.x - P0i*w0.y, a0i = P0r*w0.y + P0i*w0.x;
    float a1r = P0r*w0.z - P0i*w0.w, a1i = P0r*w0.w + P0i*w0.z;
    float a2r = P1r*w0.x - P1i*w0.y, a2i = P1r*w0.y + P1i*w0.x;
    float a3r = P1r*w0.z - P1i*w0.w, a3i = P1r*w0.w + P1i*w0.z;
    bp.h[0] = pkrtz(a0r, a0i);
    bp.h[1] = pkrtz(a1r, a1i);
    bp.h[2] = pkrtz(a2r, a2i);
    bp.h[3] = pkrtz(a3r, a3i);
}

// pack two circuits' probabilities: slot 8s+u: u<4 -> even amp 4s+u, u>=4 -> odd amp 4s+u-4
__device__ __forceinline__ F8 pack_P(const f32x4 &reE, const f32x4 &imE,
                                     const f32x4 &reO, const f32x4 &imO){
    F8 b;
    b.h[0] = pkrtz(reE[0]*reE[0] + imE[0]*imE[0], reE[1]*reE[1] + imE[1]*imE[1]);
    b.h[1] = pkrtz(reE[2]*reE[2] + imE[2]*imE[2], reE[3]*reE[3] + imE[3]*imE[3]);
    b.h[2] = pkrtz(reO[0]*reO[0] + imO[0]*imO[0], reO[1]*reO[1] + imO[1]*imO[1]);
    b.h[3] = pkrtz(reO[2]*reO[2] + imO[2]*imO[2], reO[3]*reO[3] + imO[3]*imO[3]);
    return b;
}

__device__ __forceinline__ float sel4(float a0, float a1, float a2, float a3, int s){
    float lo = (s & 1) ? a1 : a0;
    float hi = (s & 1) ? a3 : a2;
    return (s & 2) ? hi : lo;
}

__global__ void __launch_bounds__(64, 1) qlstm_kernel(
    const float* __restrict__ x, const float* __restrict__ phi,
    const float* __restrict__ Wd, const float* __restrict__ bd,
    float* __restrict__ out, int B)
{
    // gtab: 8 rows (l,i) x 48 floats (12 entries x {Ar,Ai,Br,Bi}) -- 192B stride
    __shared__ __align__(16) float gtab[384];
    __shared__ __align__(16) float ldsf[3072];
    const int UBo = 0;      // 3072 floats: U[k][m][c] complex at k*512+m*32+c*2
    const int BCo = 0;      // factor pairs alias the U region (U read only in prologue)

    const int tid  = threadIdx.x;
    const int lane = tid & 63;
    const int m    = lane & 15;
    const int grp  = lane >> 4;

    // ---------------- prologue: merged-gate table ----------------------------
    for (int idx = tid; idx < 96; idx += 64){
        int i = idx & 3, l = (idx >> 2) & 1, bb = (idx >> 3) & 1, k = idx >> 4;
        const float* pp = phi + (k*2 + l)*12 + 3*i;
        float ca, sa, cb, sb, cg, sg;
        __sincosf(0.5f*pp[0], &sa, &ca);
        __sincosf(0.5f*pp[1], &sb, &cb);
        __sincosf(0.5f*pp[2], &sg, &cg);
        float Ar, Ai, Br, Bi;
        if (bb == 0){
            float m00r = cb*ca,  m00i = sb*sa;
            float m01r = -sb*ca, m01i = -cb*sa;
            Ar = m00r*cg + m00i*sg;  Ai = m00i*cg - m00r*sg;
            Br = m01r*cg + m01i*sg;  Bi = m01i*cg - m01r*sg;
        } else {
            float m10r = sb*ca, m10i = -cb*sa;
            float m11r = cb*ca, m11i = -sb*sa;
            Ar = m11r*cg - m11i*sg;  Ai = m11i*cg + m11r*sg;
            Br = m10r*cg - m10i*sg;  Bi = m10i*cg + m10r*sg;
        }
        float* dst = gtab + (l*4 + i)*48 + (k*2 + bb)*4;
        dst[0] = Ar; dst[1] = Ai; dst[2] = Br; dst[3] = Bi;
    }
    __syncthreads();

    // CNOT-block permutation P^{-1}(m) and mid-circuit bpermute address
    const int n0 = m & 1, n1 = (m >> 1) & 1, n2 = (m >> 2) & 1, n3 = (m >> 3) & 1;
    const int pm = (n0^n1^n2) | ((n0^n2^n3) << 1) | ((n0^n1^n3) << 2) | ((n0^n1) << 3);
    const int bpaddr = ((lane & 48) | pm) * 4;

    // ---------------- prologue: build U_k columns via shuffle circuit --------
    for (int k = 0; k < 6; ++k){
        int ga0 = 0*192 + k*32 + ((m >> 0) & 1)*16;
        int ga1 = 1*192 + k*32 + ((m >> 1) & 1)*16;
        int ga2 = 2*192 + k*32 + ((m >> 2) & 1)*16;
        int ga3 = 3*192 + k*32 + ((m >> 3) & 1)*16;
        for (int cb = 0; cb < 4; ++cb){
            int c = cb*4 + grp;
            float re = (pm == c) ? 1.f : 0.f;   // P folded into columns
            float im = 0.f;
            gate_step<0>(re, im, gtab, ga0, 0);   gate_step<1>(re, im, gtab, ga1, 0);
            gate_step<2>(re, im, gtab, ga2, 0);   gate_step<3>(re, im, gtab, ga3, 0);
            re = bperm(bpaddr, re);
            im = bperm(bpaddr, im);
            gate_step<0>(re, im, gtab, ga0, 768); gate_step<1>(re, im, gtab, ga1, 768);
            gate_step<2>(re, im, gtab, ga2, 768); gate_step<3>(re, im, gtab, ga3, 768);
            float2* dst = (float2*)&ldsf[UBo + k*512 + m*32 + c*2];
            *dst = make_float2(re, im);
        }
    }
    __syncthreads();

    // ---------------- main layout: lane = (e, s) -----------------------------
    const int e = lane & 15;       // batch element (A row, B/D col)
    const int s = lane >> 4;       // own wire / k-quarter
    const int sm1 = s & 1, sm2 = s >> 1;
    const int ecol = e & 3;

    // A-fragments of U_k (re/im) -- loaded once, pinned by the aliasing stores
    F8 are[6], aim[6];
    #pragma unroll
    for (int k = 0; k < 6; ++k){
        const float* ub = &ldsf[UBo + k*512 + e*32 + s*8];
        float4 u01 = *(const float4*)ub;         // amps 4s, 4s+1 (re,im)
        float4 u23 = *(const float4*)(ub + 4);   // amps 4s+2, 4s+3
        are[k].h[0] = (f16x2){(f16)u01.x, (f16)(-u01.y)};
        are[k].h[1] = (f16x2){(f16)u01.z, (f16)(-u01.w)};
        are[k].h[2] = (f16x2){(f16)u23.x, (f16)(-u23.y)};
        are[k].h[3] = (f16x2){(f16)u23.z, (f16)(-u23.w)};
        aim[k].h[0] = (f16x2){(f16)u01.y, (f16)u01.x};
        aim[k].h[1] = (f16x2){(f16)u01.w, (f16)u01.z};
        aim[k].h[2] = (f16x2){(f16)u23.y, (f16)u23.x};
        aim[k].h[3] = (f16x2){(f16)u23.w, (f16)u23.z};
    }
    __syncthreads();   // all lanes done reading U before anyone overwrites it

    // R8-style packed sign fragment: lane (e,s) output regs 0,1 = ev_s(even ckt), 2,3 = ev_s(odd)
    F8 asig;
    {
        int q = e >> 2;
        bool evenrows = (e & 3) < 2;
        #pragma unroll
        for (int j = 0; j < 8; ++j){
            int amp = 4*s + (j & 3);
            float v = 0.f;
            if (evenrows == (j < 4))
                v = ((amp >> q) & 1) ? -1.f : 1.f;
            asig.v[j] = (f16)v;
        }
    }
    // all-wire sign fragments: evX[j] = ev of wire j (even / odd circuit)
    F8 asigF, asigI;
    #pragma unroll
    for (int u = 0; u < 8; ++u){
        int amp = 4*s + (u & 3);
        float sg = ((amp >> ecol) & 1) ? -1.f : 1.f;
        asigF.v[u] = (f16)(u < 4 ? sg : 0.f);
        asigI.v[u] = (f16)(u >= 4 ? sg : 0.f);
    }

    // A_z (x-only): rows 4q..4q+3 all = Wd column q (k<16) -> dzx[0] = z_x(own wire)
    F8 az;
    #pragma unroll
    for (int j = 0; j < 4; ++j){
        int k0 = s*8 + 2*j, k1 = k0 + 1;
        float v0 = (k0 < 16) ? Wd[k0*20 + (e >> 2)] : 0.f;
        float v1 = (k1 < 16) ? Wd[k1*20 + (e >> 2)] : 0.f;
        az.h[j] = (f16x2){(f16)v0, (f16)v1};
    }
    const float bdv = bd[s];
    // Wd_h column s in f32: z_h,s = sum_q Wd[16+q][s] * h_q
    const float4 wqs = make_float4(Wd[16*20 + s], Wd[17*20 + s],
                                   Wd[18*20 + s], Wd[19*20 + s]);

    const int b0 = blockIdx.x * NELEM;
    const float* xp = x + (size_t)(b0 + e) * TSTEPS * NFEAT;
    // lanes s>=2 feed only k-slots >=16 where az rows are 0 -> content is
    // don't-care (finite garbage * 0); point them at a safe base and drop
    // all per-step selects.
    const float* xq = (s < 2) ? (xp + s*8) : xp;
    float* yp = out + (size_t)(b0 + e) * TSTEPS * 4 + s;

    const f32x4 z4 = {0.f, 0.f, 0.f, 0.f};
    float cst = 0.f;
    f32x4 hv = z4;                  // all-wire h state (f32, replicated across s)

    // x prefetch + pipelined z_x MFMA for t=0
    float4 xa = *(const float4*)(xq);
    float4 xb = *(const float4*)(xq + 4);
    F8 bz;
    bz.h[0] = pkrtz(xa.x, xa.y);
    bz.h[1] = pkrtz(xa.z, xa.w);
    bz.h[2] = pkrtz(xb.x, xb.y);
    bz.h[3] = pkrtz(xb.z, xb.w);
    f32x4 dzx = __builtin_amdgcn_mfma_f32_16x16x32_f16(az.v, bz.v, z4, 0, 0, 0);
    xa = *(const float4*)(xq + NFEAT);
    xb = *(const float4*)(xq + NFEAT + 4);

    #pragma clang loop unroll(disable)
    for (int t = 0; t < TSTEPS; ++t){
        // ---- z (own wire) = z_x (pipelined MFMA) + Wd_h^T h (f32 VALU) + bd ----
        float zval = dzx[0] + bdv
                   + wqs.x*hv[0] + wqs.y*hv[1] + wqs.z*hv[2] + wqs.w*hv[3];
        float usel = 1.f - 2.f*frcp(__expf(zval) + 1.f);
        float F0r, F0i, F1r, F1i;
        factors(usel, F0r, F0i, F1r, F1i);
        write_F(&ldsf[BCo], e, s, F0r, F0i, F1r, F1i);
        cfence();
        F8 bp;
        build_psi(&ldsf[BCo], e, sm1, sm2, bp);

        // ---- phase 1: f,i,Cg,o = 8 U-MFMAs + 2 EV-MFMAs (packed, own wire) ----
        f32x4 dre[4], dim4[4];
        #pragma unroll
        for (int k = 0; k < 4; ++k){
            dre[k]  = __builtin_amdgcn_mfma_f32_16x16x32_f16(are[k].v, bp.v, z4, 0,0,0);
            dim4[k] = __builtin_amdgcn_mfma_f32_16x16x32_f16(aim[k].v, bp.v, z4, 0,0,0);
        }
        F8 pb1 = pack_P(dre[0], dim4[0], dre[1], dim4[1]);   // f (even), i (odd)
        F8 pb2 = pack_P(dre[2], dim4[2], dre[3], dim4[3]);   // Cg, o
        f32x4 ev1 = __builtin_amdgcn_mfma_f32_16x16x32_f16(asig.v, pb1.v, z4, 0,0,0);
        f32x4 ev2 = __builtin_amdgcn_mfma_f32_16x16x32_f16(asig.v, pb2.v, z4, 0,0,0);

        // ---- pipelined z_x for t+1 ----
        if (t + 1 < TSTEPS){
            bz.h[0] = pkrtz(xa.x, xa.y);
            bz.h[1] = pkrtz(xa.z, xa.w);
            bz.h[2] = pkrtz(xb.x, xb.y);
            bz.h[3] = pkrtz(xb.z, xb.w);
            dzx = __builtin_amdgcn_mfma_f32_16x16x32_f16(az.v, bz.v, z4, 0,0,0);
            if (t + 2 < TSTEPS){
                xa = *(const float4*)(xq + (t+2)*NFEAT);
                xb = *(const float4*)(xq + (t+2)*NFEAT + 4);
            }
        }

        // ---- LSTM pointwise (own wire s only) ----
        float fg = sigm(ev1[0]), ig = sigm(ev1[2]), Cg = sigm(ev2[0]), og = sigm(ev2[2]);
        cst = fg*cst + ig*Cg;
        float rs = og * tanh_f(cst);
        factors(rs, F0r, F0i, F1r, F1i);
        write_F(&ldsf[BCo], e, s, F0r, F0i, F1r, F1i);
        cfence();
        F8 bpp;
        build_psi(&ldsf[BCo], e, sm1, sm2, bpp);

        // ---- phase 2: h (k=4), y (k=5) = 4 U-MFMAs + 2 EV-MFMAs ----
        f32x4 hre = __builtin_amdgcn_mfma_f32_16x16x32_f16(are[4].v, bpp.v, z4, 0,0,0);
        f32x4 him = __builtin_amdgcn_mfma_f32_16x16x32_f16(aim[4].v, bpp.v, z4, 0,0,0);
        f32x4 yre = __builtin_amdgcn_mfma_f32_16x16x32_f16(are[5].v, bpp.v, z4, 0,0,0);
        f32x4 yim = __builtin_amdgcn_mfma_f32_16x16x32_f16(aim[5].v, bpp.v, z4, 0,0,0);
        F8 b3 = pack_P(hre, him, yre, yim);                 // h (even), y (odd)
        hv = __builtin_amdgcn_mfma_f32_16x16x32_f16(asigF.v, b3.v, z4, 0,0,0);  // all-wire h
        f32x4 evY = __builtin_amdgcn_mfma_f32_16x16x32_f16(asigI.v, b3.v, z4, 0,0,0);

        // ---- y scatter (own wire, off critical path) ----
        yp[t*4] = sel4(evY[0], evY[1], evY[2], evY[3], s);
    }

    // final c (own wire), h (select own wire from all-wire state)
    size_t cbase = (size_t)B * TSTEPS * 4;
    out[cbase + (size_t)(b0 + e)*4 + s] = cst;
    out[cbase + (size_t)B*4 + (size_t)(b0 + e)*4 + s] = sel4(hv[0], hv[1], hv[2], hv[3], s);
}

extern "C" void kernel_launch(void* const* d_in, const int* in_sizes, int n_in,
                              void* d_out, int out_size, void* d_ws, size_t ws_size,
                              hipStream_t stream) {
    const float* x   = (const float*)d_in[0];
    const float* phi = (const float*)d_in[1];
    const float* Wd  = (const float*)d_in[2];
    const float* bd  = (const float*)d_in[3];
    float* out = (float*)d_out;
    int B = in_sizes[0] / (TSTEPS * NFEAT);   // 4096
    int blocks = B / NELEM;                   // 256 blocks x 1 wave x 16 elems
    hipLaunchKernelGGL(qlstm_kernel, dim3(blocks), dim3(64), 0, stream,
                       x, phi, Wd, bd, out, B);
}

// Round 18
// 110.275 us; speedup vs baseline: 1.3137x; 1.1335x over previous
//
#include <hip/hip_runtime.h>
#include <math.h>

#define TSTEPS 128
#define NFEAT 16
#define NELEM 16   // batch elements per wave

typedef __fp16 f16;
typedef __fp16 f16x2 __attribute__((ext_vector_type(2)));
typedef __fp16 f16x8 __attribute__((ext_vector_type(8)));
typedef float f32x4 __attribute__((ext_vector_type(4)));

union F8 { f16x8 v; f16x2 h[4]; };

__device__ __forceinline__ float frcp(float x){ return __builtin_amdgcn_rcpf(x); }
__device__ __forceinline__ float frsq(float x){ return __builtin_amdgcn_rsqf(x); }
__device__ __forceinline__ float bperm(int addr, float v){
    return __int_as_float(__builtin_amdgcn_ds_bpermute(addr, __float_as_int(v)));
}
__device__ __forceinline__ f16x2 pkrtz(float a, float b){
    return __builtin_amdgcn_cvt_pkrtz(a, b);
}
__device__ __forceinline__ float dpp_xor1(float v){
    return __int_as_float(__builtin_amdgcn_update_dpp(0, __float_as_int(v), 0xB1, 0xF, 0xF, true));
}
__device__ __forceinline__ float dpp_xor2(float v){
    return __int_as_float(__builtin_amdgcn_update_dpp(0, __float_as_int(v), 0x4E, 0xF, 0xF, true));
}
__device__ __forceinline__ float swz_xor4(float v){
    return __int_as_float(__builtin_amdgcn_ds_swizzle(__float_as_int(v), 0x101F));
}
__device__ __forceinline__ float swz_xor8(float v){
    return __int_as_float(__builtin_amdgcn_ds_swizzle(__float_as_int(v), 0x201F));
}
template<int MASK> __device__ __forceinline__ float pshfl(float v){
    if constexpr (MASK == 1) return dpp_xor1(v);
    else if constexpr (MASK == 2) return dpp_xor2(v);
    else if constexpr (MASK == 4) return swz_xor4(v);
    else return swz_xor8(v);
}
__device__ __forceinline__ void cfence(){ __asm__ __volatile__("" ::: "memory"); }

__device__ __forceinline__ float sigm(float x){ return frcp(1.f + __expf(-x)); }
__device__ __forceinline__ float tanh_f(float x){ return 1.f - 2.f * frcp(__expf(2.f*x) + 1.f); }

// merged RZ*RY*RX on wire I (prologue / U-construction only)
template<int I>
__device__ __forceinline__ void gate_step(float &re, float &im,
                                          const float* gt, int ai, int loff){
    const float4 g = *(const float4*)((const char*)gt + ai + loff);
    float pre = pshfl<(1 << I)>(re);
    float pim = pshfl<(1 << I)>(im);
    float nre = g.x*re - g.y*im + g.z*pre - g.w*pim;
    float nim = g.x*im + g.y*re + g.z*pim + g.w*pre;
    re = nre; im = nim;
}

// fused factor products: F(0) = (c1c2, -c1s2), F(1) = (s1c2, s1s2)
// for angles atan(u) (RY) and atan(u^2) (RZ) -- 3 trans instead of 4
__device__ __forceinline__ void factors(float u, float &F0r, float &F0i,
                                        float &F1r, float &F1i){
    float u2  = u * u;
    float ca1 = frsq(1.f + u2);          // cos(atan u)
    float ca2 = frsq(1.f + u2*u2);       // cos(atan u^2)
    float x1  = (1.f + ca1) * 0.5f;      // cos^2 of half-angles
    float x2  = (1.f + ca2) * 0.5f;
    float x12 = x1 * x2;
    float t   = frsq(x12);
    float a1  = u  * ca1 * 0.5f;
    float a2  = u2 * ca2 * 0.5f;
    F0r = x12 * t;                       // c1*c2
    F0i = -(a2 * x1 * t);                // -(c1*s2)
    F1r = a1 * x2 * t;                   // s1*c2
    F1i = a1 * a2 * t;                   // s1*s2
}

// lane (e,s) emits complex factors F_s(0), F_s(1) of its wire into LDS
__device__ __forceinline__ void write_F(float* bc, int e, int s,
                                        float F0r, float F0i, float F1r, float F1i){
    float4 w;
    w.x = F0r; w.y = F0i; w.z = F1r; w.w = F1i;
    *(float4*)(bc + e*20 + s*4) = w;
}

// lane (e,s) builds its 4 amplitudes a=4s..4s+3 of elem e's init state (B-fragment)
__device__ __forceinline__ void build_psi(const float* bc, int e, int sm1, int sm2,
                                          F8 &bp){
    const float4 w0 = *(const float4*)(bc + e*20);               // wire0: F(0),F(1)
    const float4 w1 = *(const float4*)(bc + e*20 + 4);           // wire1
    const float2 F2 = *(const float2*)(bc + e*20 + 8  + sm1*2);  // F_2(s&1)
    const float2 F3 = *(const float2*)(bc + e*20 + 12 + sm2*2);  // F_3(s>>1)
    float pr = F2.x*F3.x - F2.y*F3.y;
    float pi = F2.x*F3.y + F2.y*F3.x;                            // prefix
    float P0r = pr*w1.x - pi*w1.y, P0i = pr*w1.y + pi*w1.x;      // prefix*F1(0)
    float P1r = pr*w1.z - pi*w1.w, P1i = pr*w1.w + pi*w1.z;      // prefix*F1(1)
    float a0r = P0r*w0.x - P0i*w0.y, a0i = P0r*w0.y + P0i*w0.x;
    float a1r = P0r*w0.z - P0i*w0.w, a1i = P0r*w0.w + P0i*w0.z;
    float a2r = P1r*w0.x - P1i*w0.y, a2i = P1r*w0.y + P1i*w0.x;
    float a3r = P1r*w0.z - P1i*w0.w, a3i = P1r*w0.w + P1i*w0.z;
    bp.h[0] = pkrtz(a0r, a0i);
    bp.h[1] = pkrtz(a1r, a1i);
    bp.h[2] = pkrtz(a2r, a2i);
    bp.h[3] = pkrtz(a3r, a3i);
}

// pack two circuits' probabilities via packed-f32 vector math:
// slot 8s+u: u<4 -> even amp 4s+u, u>=4 -> odd amp 4s+u-4
__device__ __forceinline__ F8 pack_P(const f32x4 &reE, const f32x4 &imE,
                                     const f32x4 &reO, const f32x4 &imO){
    f32x4 pE = reE*reE + imE*imE;   // elementwise -> v_pk_fma_f32 candidates
    f32x4 pO = reO*reO + imO*imO;
    F8 b;
    b.h[0] = pkrtz(pE[0], pE[1]);
    b.h[1] = pkrtz(pE[2], pE[3]);
    b.h[2] = pkrtz(pO[0], pO[1]);
    b.h[3] = pkrtz(pO[2], pO[3]);
    return b;
}

__device__ __forceinline__ float sel4(float a0, float a1, float a2, float a3, int s){
    float lo = (s & 1) ? a1 : a0;
    float hi = (s & 1) ? a3 : a2;
    return (s & 2) ? hi : lo;
}

__global__ void __launch_bounds__(64, 1) qlstm_kernel(
    const float* __restrict__ x, const float* __restrict__ phi,
    const float* __restrict__ Wd, const float* __restrict__ bd,
    float* __restrict__ out, int B)
{
    // gtab: 8 rows (l,i) x 48 floats (12 entries x {Ar,Ai,Br,Bi}) -- 192B stride
    __shared__ __align__(16) float gtab[384];
    __shared__ __align__(16) float ldsf[3072];
    const int UBo = 0;      // 3072 floats: U[k][m][c] complex at k*512+m*32+c*2
    const int BCo = 0;      // factor pairs alias the U region (U read only in prologue)

    const int tid  = threadIdx.x;
    const int lane = tid & 63;
    const int m    = lane & 15;
    const int grp  = lane >> 4;

    // ---------------- prologue: merged-gate table ----------------------------
    for (int idx = tid; idx < 96; idx += 64){
        int i = idx & 3, l = (idx >> 2) & 1, bb = (idx >> 3) & 1, k = idx >> 4;
        const float* pp = phi + (k*2 + l)*12 + 3*i;
        float ca, sa, cb, sb, cg, sg;
        __sincosf(0.5f*pp[0], &sa, &ca);
        __sincosf(0.5f*pp[1], &sb, &cb);
        __sincosf(0.5f*pp[2], &sg, &cg);
        float Ar, Ai, Br, Bi;
        if (bb == 0){
            float m00r = cb*ca,  m00i = sb*sa;
            float m01r = -sb*ca, m01i = -cb*sa;
            Ar = m00r*cg + m00i*sg;  Ai = m00i*cg - m00r*sg;
            Br = m01r*cg + m01i*sg;  Bi = m01i*cg - m01r*sg;
        } else {
            float m10r = sb*ca, m10i = -cb*sa;
            float m11r = cb*ca, m11i = -sb*sa;
            Ar = m11r*cg - m11i*sg;  Ai = m11i*cg + m11r*sg;
            Br = m10r*cg - m10i*sg;  Bi = m10i*cg + m10r*sg;
        }
        float* dst = gtab + (l*4 + i)*48 + (k*2 + bb)*4;
        dst[0] = Ar; dst[1] = Ai; dst[2] = Br; dst[3] = Bi;
    }
    __syncthreads();

    // CNOT-block permutation P^{-1}(m) and mid-circuit bpermute address
    const int n0 = m & 1, n1 = (m >> 1) & 1, n2 = (m >> 2) & 1, n3 = (m >> 3) & 1;
    const int pm = (n0^n1^n2) | ((n0^n2^n3) << 1) | ((n0^n1^n3) << 2) | ((n0^n1) << 3);
    const int bpaddr = ((lane & 48) | pm) * 4;

    // ---------------- prologue: build U_k columns via shuffle circuit --------
    for (int k = 0; k < 6; ++k){
        int ga0 = 0*192 + k*32 + ((m >> 0) & 1)*16;
        int ga1 = 1*192 + k*32 + ((m >> 1) & 1)*16;
        int ga2 = 2*192 + k*32 + ((m >> 2) & 1)*16;
        int ga3 = 3*192 + k*32 + ((m >> 3) & 1)*16;
        for (int cb = 0; cb < 4; ++cb){
            int c = cb*4 + grp;
            float re = (pm == c) ? 1.f : 0.f;   // P folded into columns
            float im = 0.f;
            gate_step<0>(re, im, gtab, ga0, 0);   gate_step<1>(re, im, gtab, ga1, 0);
            gate_step<2>(re, im, gtab, ga2, 0);   gate_step<3>(re, im, gtab, ga3, 0);
            re = bperm(bpaddr, re);
            im = bperm(bpaddr, im);
            gate_step<0>(re, im, gtab, ga0, 768); gate_step<1>(re, im, gtab, ga1, 768);
            gate_step<2>(re, im, gtab, ga2, 768); gate_step<3>(re, im, gtab, ga3, 768);
            float2* dst = (float2*)&ldsf[UBo + k*512 + m*32 + c*2];
            *dst = make_float2(re, im);
        }
    }
    __syncthreads();

    // ---------------- main layout: lane = (e, s) -----------------------------
    const int e = lane & 15;       // batch element (A row, B/D col)
    const int s = lane >> 4;       // own wire / k-quarter
    const int sm1 = s & 1, sm2 = s >> 1;
    const int ecol = e & 3;

    // A-fragments of U_k (re/im) -- loaded once, pinned by the aliasing stores
    F8 are[6], aim[6];
    #pragma unroll
    for (int k = 0; k < 6; ++k){
        const float* ub = &ldsf[UBo + k*512 + e*32 + s*8];
        float4 u01 = *(const float4*)ub;         // amps 4s, 4s+1 (re,im)
        float4 u23 = *(const float4*)(ub + 4);   // amps 4s+2, 4s+3
        are[k].h[0] = (f16x2){(f16)u01.x, (f16)(-u01.y)};
        are[k].h[1] = (f16x2){(f16)u01.z, (f16)(-u01.w)};
        are[k].h[2] = (f16x2){(f16)u23.x, (f16)(-u23.y)};
        are[k].h[3] = (f16x2){(f16)u23.z, (f16)(-u23.w)};
        aim[k].h[0] = (f16x2){(f16)u01.y, (f16)u01.x};
        aim[k].h[1] = (f16x2){(f16)u01.w, (f16)u01.z};
        aim[k].h[2] = (f16x2){(f16)u23.y, (f16)u23.x};
        aim[k].h[3] = (f16x2){(f16)u23.w, (f16)u23.z};
    }
    __syncthreads();   // all lanes done reading U before anyone overwrites it

    // R8-style packed sign fragment: lane (e,s) output regs 0,1 = ev_s(even ckt), 2,3 = ev_s(odd)
    F8 asig;
    {
        int q = e >> 2;
        bool evenrows = (e & 3) < 2;
        #pragma unroll
        for (int j = 0; j < 8; ++j){
            int amp = 4*s + (j & 3);
            float v = 0.f;
            if (evenrows == (j < 4))
                v = ((amp >> q) & 1) ? -1.f : 1.f;
            asig.v[j] = (f16)v;
        }
    }
    // all-wire sign fragments: evX[j] = ev of wire j (even / odd circuit)
    F8 asigF, asigI;
    #pragma unroll
    for (int u = 0; u < 8; ++u){
        int amp = 4*s + (u & 3);
        float sg = ((amp >> ecol) & 1) ? -1.f : 1.f;
        asigF.v[u] = (f16)(u < 4 ? sg : 0.f);
        asigI.v[u] = (f16)(u >= 4 ? sg : 0.f);
    }

    // A_z (x-only): rows 4q..4q+3 all = Wd column q (k<16) -> dzx[0] = z_x(own wire)
    F8 az;
    #pragma unroll
    for (int j = 0; j < 4; ++j){
        int k0 = s*8 + 2*j, k1 = k0 + 1;
        float v0 = (k0 < 16) ? Wd[k0*20 + (e >> 2)] : 0.f;
        float v1 = (k1 < 16) ? Wd[k1*20 + (e >> 2)] : 0.f;
        az.h[j] = (f16x2){(f16)v0, (f16)v1};
    }
    const float bdv = bd[s];
    // Wd_h column s in f32: z_h,s = sum_q Wd[16+q][s] * h_q
    const float4 wqs = make_float4(Wd[16*20 + s], Wd[17*20 + s],
                                   Wd[18*20 + s], Wd[19*20 + s]);

    const int b0 = blockIdx.x * NELEM;
    const float* xp = x + (size_t)(b0 + e) * TSTEPS * NFEAT;
    // lanes s>=2 feed only k-slots >=16 where az rows are 0 -> content don't-care
    const float* xq = (s < 2) ? (xp + s*8) : xp;
    float* yp = out + (size_t)(b0 + e) * TSTEPS * 4 + s;

    const f32x4 z4 = {0.f, 0.f, 0.f, 0.f};
    float cst = 0.f;
    f32x4 hv = z4;                  // all-wire h state (f32, replicated across s)

    // x prefetch + pipelined z_x MFMA for t=0
    float4 xa = *(const float4*)(xq);
    float4 xb = *(const float4*)(xq + 4);
    F8 bz;
    bz.h[0] = pkrtz(xa.x, xa.y);
    bz.h[1] = pkrtz(xa.z, xa.w);
    bz.h[2] = pkrtz(xb.x, xb.y);
    bz.h[3] = pkrtz(xb.z, xb.w);
    f32x4 dzx = __builtin_amdgcn_mfma_f32_16x16x32_f16(az.v, bz.v, z4, 0, 0, 0);
    xa = *(const float4*)(xq + NFEAT);
    xb = *(const float4*)(xq + NFEAT + 4);

    #pragma clang loop unroll(disable)
    for (int t = 0; t < TSTEPS; ++t){
        // ---- z (own wire) = z_x (pipelined MFMA) + Wd_h^T h (f32 VALU) + bd ----
        float zval = dzx[0] + bdv
                   + wqs.x*hv[0] + wqs.y*hv[1] + wqs.z*hv[2] + wqs.w*hv[3];
        float usel = 1.f - 2.f*frcp(__expf(zval) + 1.f);
        float F0r, F0i, F1r, F1i;
        factors(usel, F0r, F0i, F1r, F1i);
        write_F(&ldsf[BCo], e, s, F0r, F0i, F1r, F1i);
        cfence();
        F8 bp;
        build_psi(&ldsf[BCo], e, sm1, sm2, bp);

        // ---- phase 1: f,i,Cg,o = 8 U-MFMAs + 2 EV-MFMAs (packed, own wire) ----
        f32x4 dre[4], dim4[4];
        #pragma unroll
        for (int k = 0; k < 4; ++k){
            dre[k]  = __builtin_amdgcn_mfma_f32_16x16x32_f16(are[k].v, bp.v, z4, 0,0,0);
            dim4[k] = __builtin_amdgcn_mfma_f32_16x16x32_f16(aim[k].v, bp.v, z4, 0,0,0);
        }
        F8 pb1 = pack_P(dre[0], dim4[0], dre[1], dim4[1]);   // f (even), i (odd)
        F8 pb2 = pack_P(dre[2], dim4[2], dre[3], dim4[3]);   // Cg, o
        f32x4 ev1 = __builtin_amdgcn_mfma_f32_16x16x32_f16(asig.v, pb1.v, z4, 0,0,0);
        f32x4 ev2 = __builtin_amdgcn_mfma_f32_16x16x32_f16(asig.v, pb2.v, z4, 0,0,0);

        // ---- pipelined z_x for t+1 ----
        if (t + 1 < TSTEPS){
            bz.h[0] = pkrtz(xa.x, xa.y);
            bz.h[1] = pkrtz(xa.z, xa.w);
            bz.h[2] = pkrtz(xb.x, xb.y);
            bz.h[3] = pkrtz(xb.z, xb.w);
            dzx = __builtin_amdgcn_mfma_f32_16x16x32_f16(az.v, bz.v, z4, 0,0,0);
            if (t + 2 < TSTEPS){
                xa = *(const float4*)(xq + (t+2)*NFEAT);
                xb = *(const float4*)(xq + (t+2)*NFEAT + 4);
            }
        }

        // ---- LSTM pointwise (own wire s only) ----
        float fg = sigm(ev1[0]), ig = sigm(ev1[2]), Cg = sigm(ev2[0]), og = sigm(ev2[2]);
        cst = fg*cst + ig*Cg;
        float rs = og * tanh_f(cst);
        factors(rs, F0r, F0i, F1r, F1i);
        write_F(&ldsf[BCo], e, s, F0r, F0i, F1r, F1i);
        cfence();
        F8 bpp;
        build_psi(&ldsf[BCo], e, sm1, sm2, bpp);

        // ---- phase 2: h (k=4), y (k=5) = 4 U-MFMAs + 2 EV-MFMAs ----
        f32x4 hre = __builtin_amdgcn_mfma_f32_16x16x32_f16(are[4].v, bpp.v, z4, 0,0,0);
        f32x4 him = __builtin_amdgcn_mfma_f32_16x16x32_f16(aim[4].v, bpp.v, z4, 0,0,0);
        f32x4 yre = __builtin_amdgcn_mfma_f32_16x16x32_f16(are[5].v, bpp.v, z4, 0,0,0);
        f32x4 yim = __builtin_amdgcn_mfma_f32_16x16x32_f16(aim[5].v, bpp.v, z4, 0,0,0);
        F8 b3 = pack_P(hre, him, yre, yim);                 // h (even), y (odd)
        hv = __builtin_amdgcn_mfma_f32_16x16x32_f16(asigF.v, b3.v, z4, 0,0,0);  // all-wire h
        f32x4 evY = __builtin_amdgcn_mfma_f32_16x16x32_f16(asigI.v, b3.v, z4, 0,0,0);

        // ---- y scatter (own wire, off critical path) ----
        yp[t*4] = sel4(evY[0], evY[1], evY[2], evY[3], s);
    }

    // final c (own wire), h (select own wire from all-wire state)
    size_t cbase = (size_t)B * TSTEPS * 4;
    out[cbase + (size_t)(b0 + e)*4 + s] = cst;
    out[cbase + (size_t)B*4 + (size_t)(b0 + e)*4 + s] = sel4(hv[0], hv[1], hv[2], hv[3], s);
}

extern "C" void kernel_launch(void* const* d_in, const int* in_sizes, int n_in,
                              void* d_out, int out_size, void* d_ws, size_t ws_size,
                              hipStream_t stream) {
    const float* x   = (const float*)d_in[0];
    const float* phi = (const float*)d_in[1];
    const float* Wd  = (const float*)d_in[2];
    const float* bd  = (const float*)d_in[3];
    float* out = (float*)d_out;
    int B = in_sizes[0] / (TSTEPS * NFEAT);   // 4096
    int blocks = B / NELEM;                   // 256 blocks x 1 wave x 16 elems
    hipLaunchKernelGGL(qlstm_kernel, dim3(blocks), dim3(64), 0, stream,
                       x, phi, Wd, bd, out, B);
}

// Round 19
// 109.626 us; speedup vs baseline: 1.3215x; 1.0059x over previous
//
#include <hip/hip_runtime.h>
#include <math.h>

#define TSTEPS 128
#define NFEAT 16
#define NELEM 16   // batch elements per wave

typedef __fp16 f16;
typedef __fp16 f16x2 __attribute__((ext_vector_type(2)));
typedef __fp16 f16x8 __attribute__((ext_vector_type(8)));
typedef float f32x2 __attribute__((ext_vector_type(2)));
typedef float f32x4 __attribute__((ext_vector_type(4)));

union F8 { f16x8 v; f16x2 h[4]; };

__device__ __forceinline__ float frcp(float x){ return __builtin_amdgcn_rcpf(x); }
__device__ __forceinline__ float frsq(float x){ return __builtin_amdgcn_rsqf(x); }
__device__ __forceinline__ float bperm(int addr, float v){
    return __int_as_float(__builtin_amdgcn_ds_bpermute(addr, __float_as_int(v)));
}
__device__ __forceinline__ f16x2 pkrtz(float a, float b){
    return __builtin_amdgcn_cvt_pkrtz(a, b);
}
__device__ __forceinline__ float dpp_xor1(float v){
    return __int_as_float(__builtin_amdgcn_update_dpp(0, __float_as_int(v), 0xB1, 0xF, 0xF, true));
}
__device__ __forceinline__ float dpp_xor2(float v){
    return __int_as_float(__builtin_amdgcn_update_dpp(0, __float_as_int(v), 0x4E, 0xF, 0xF, true));
}
__device__ __forceinline__ float swz_xor4(float v){
    return __int_as_float(__builtin_amdgcn_ds_swizzle(__float_as_int(v), 0x101F));
}
__device__ __forceinline__ float swz_xor8(float v){
    return __int_as_float(__builtin_amdgcn_ds_swizzle(__float_as_int(v), 0x201F));
}
template<int MASK> __device__ __forceinline__ float pshfl(float v){
    if constexpr (MASK == 1) return dpp_xor1(v);
    else if constexpr (MASK == 2) return dpp_xor2(v);
    else if constexpr (MASK == 4) return swz_xor4(v);
    else return swz_xor8(v);
}
__device__ __forceinline__ void cfence(){ __asm__ __volatile__("" ::: "memory"); }

__device__ __forceinline__ float sigm(float x){ return frcp(1.f + __expf(-x)); }
__device__ __forceinline__ float tanh_f(float x){ return 1.f - 2.f * frcp(__expf(2.f*x) + 1.f); }

// packed complex multiply: (a.x*b.x - a.y*b.y, a.x*b.y + a.y*b.x)
// maps to v_pk_mul_f32 + v_pk_fma_f32 (swap/neg via op_sel modifiers)
__device__ __forceinline__ f32x2 cmul(f32x2 a, f32x2 b){
    f32x2 bs = {b.y, b.x};
    f32x2 ar = {a.x, a.x};
    f32x2 ai = {-a.y, a.y};
    return ar*b + ai*bs;
}

// merged RZ*RY*RX on wire I (prologue / U-construction only)
template<int I>
__device__ __forceinline__ void gate_step(float &re, float &im,
                                          const float* gt, int ai, int loff){
    const float4 g = *(const float4*)((const char*)gt + ai + loff);
    float pre = pshfl<(1 << I)>(re);
    float pim = pshfl<(1 << I)>(im);
    float nre = g.x*re - g.y*im + g.z*pre - g.w*pim;
    float nim = g.x*im + g.y*re + g.z*pim + g.w*pre;
    re = nre; im = nim;
}

// fused factor products: F(0) = (c1c2, -c1s2), F(1) = (s1c2, s1s2)
// for angles atan(u) (RY) and atan(u^2) (RZ) -- 3 trans instead of 4
__device__ __forceinline__ void factors(float u, float &F0r, float &F0i,
                                        float &F1r, float &F1i){
    float u2  = u * u;
    float ca1 = frsq(1.f + u2);          // cos(atan u)
    float ca2 = frsq(1.f + u2*u2);       // cos(atan u^2)
    float x1  = (1.f + ca1) * 0.5f;      // cos^2 of half-angles
    float x2  = (1.f + ca2) * 0.5f;
    float x12 = x1 * x2;
    float t   = frsq(x12);
    float a1  = u  * ca1 * 0.5f;
    float a2  = u2 * ca2 * 0.5f;
    F0r = x12 * t;                       // c1*c2
    F0i = -(a2 * x1 * t);                // -(c1*s2)
    F1r = a1 * x2 * t;                   // s1*c2
    F1i = a1 * a2 * t;                   // s1*s2
}

// lane (e,s) emits complex factors F_s(0), F_s(1) of its wire into LDS
__device__ __forceinline__ void write_F(float* bc, int e, int s,
                                        float F0r, float F0i, float F1r, float F1i){
    float4 w;
    w.x = F0r; w.y = F0i; w.z = F1r; w.w = F1i;
    *(float4*)(bc + e*20 + s*4) = w;
}

// lane (e,s) builds its 4 amplitudes a=4s..4s+3 of elem e's init state (B-fragment)
// complex arithmetic via packed-f32 (v_pk_mul/v_pk_fma candidates)
__device__ __forceinline__ void build_psi(const float* bc, int e, int sm1, int sm2,
                                          F8 &bp){
    const float4 w0 = *(const float4*)(bc + e*20);               // wire0: F(0),F(1)
    const float4 w1 = *(const float4*)(bc + e*20 + 4);           // wire1
    const f32x2 F2 = *(const f32x2*)(bc + e*20 + 8  + sm1*2);    // F_2(s&1)
    const f32x2 F3 = *(const f32x2*)(bc + e*20 + 12 + sm2*2);    // F_3(s>>1)
    f32x2 w00 = {w0.x, w0.y}, w01 = {w0.z, w0.w};
    f32x2 w10 = {w1.x, w1.y}, w11 = {w1.z, w1.w};
    f32x2 pre = cmul(F2, F3);                                    // prefix
    f32x2 P0 = cmul(pre, w10);                                   // prefix*F1(0)
    f32x2 P1 = cmul(pre, w11);                                   // prefix*F1(1)
    f32x2 a0 = cmul(P0, w00);
    f32x2 a1 = cmul(P0, w01);
    f32x2 a2 = cmul(P1, w00);
    f32x2 a3 = cmul(P1, w01);
    bp.h[0] = pkrtz(a0.x, a0.y);
    bp.h[1] = pkrtz(a1.x, a1.y);
    bp.h[2] = pkrtz(a2.x, a2.y);
    bp.h[3] = pkrtz(a3.x, a3.y);
}

// pack two circuits' probabilities via packed-f32 vector math:
// slot 8s+u: u<4 -> even amp 4s+u, u>=4 -> odd amp 4s+u-4
__device__ __forceinline__ F8 pack_P(const f32x4 &reE, const f32x4 &imE,
                                     const f32x4 &reO, const f32x4 &imO){
    f32x4 pE = reE*reE + imE*imE;
    f32x4 pO = reO*reO + imO*imO;
    F8 b;
    b.h[0] = pkrtz(pE[0], pE[1]);
    b.h[1] = pkrtz(pE[2], pE[3]);
    b.h[2] = pkrtz(pO[0], pO[1]);
    b.h[3] = pkrtz(pO[2], pO[3]);
    return b;
}

__device__ __forceinline__ float sel4(float a0, float a1, float a2, float a3, int s){
    float lo = (s & 1) ? a1 : a0;
    float hi = (s & 1) ? a3 : a2;
    return (s & 2) ? hi : lo;
}

__global__ void __launch_bounds__(64, 1) qlstm_kernel(
    const float* __restrict__ x, const float* __restrict__ phi,
    const float* __restrict__ Wd, const float* __restrict__ bd,
    float* __restrict__ out, int B)
{
    // gtab: 8 rows (l,i) x 48 floats (12 entries x {Ar,Ai,Br,Bi}) -- 192B stride
    __shared__ __align__(16) float gtab[384];
    __shared__ __align__(16) float ldsf[3072];
    const int UBo = 0;      // 3072 floats: U[k][m][c] complex at k*512+m*32+c*2
    const int BCo = 0;      // factor pairs alias the U region (U read only in prologue)

    const int tid  = threadIdx.x;
    const int lane = tid & 63;
    const int m    = lane & 15;
    const int grp  = lane >> 4;

    // ---------------- prologue: merged-gate table ----------------------------
    for (int idx = tid; idx < 96; idx += 64){
        int i = idx & 3, l = (idx >> 2) & 1, bb = (idx >> 3) & 1, k = idx >> 4;
        const float* pp = phi + (k*2 + l)*12 + 3*i;
        float ca, sa, cb, sb, cg, sg;
        __sincosf(0.5f*pp[0], &sa, &ca);
        __sincosf(0.5f*pp[1], &sb, &cb);
        __sincosf(0.5f*pp[2], &sg, &cg);
        float Ar, Ai, Br, Bi;
        if (bb == 0){
            float m00r = cb*ca,  m00i = sb*sa;
            float m01r = -sb*ca, m01i = -cb*sa;
            Ar = m00r*cg + m00i*sg;  Ai = m00i*cg - m00r*sg;
            Br = m01r*cg + m01i*sg;  Bi = m01i*cg - m01r*sg;
        } else {
            float m10r = sb*ca, m10i = -cb*sa;
            float m11r = cb*ca, m11i = -sb*sa;
            Ar = m11r*cg - m11i*sg;  Ai = m11i*cg + m11r*sg;
            Br = m10r*cg - m10i*sg;  Bi = m10i*cg + m10r*sg;
        }
        float* dst = gtab + (l*4 + i)*48 + (k*2 + bb)*4;
        dst[0] = Ar; dst[1] = Ai; dst[2] = Br; dst[3] = Bi;
    }
    __syncthreads();

    // CNOT-block permutation P^{-1}(m) and mid-circuit bpermute address
    const int n0 = m & 1, n1 = (m >> 1) & 1, n2 = (m >> 2) & 1, n3 = (m >> 3) & 1;
    const int pm = (n0^n1^n2) | ((n0^n2^n3) << 1) | ((n0^n1^n3) << 2) | ((n0^n1) << 3);
    const int bpaddr = ((lane & 48) | pm) * 4;

    // ---------------- prologue: build U_k columns via shuffle circuit --------
    for (int k = 0; k < 6; ++k){
        int ga0 = 0*192 + k*32 + ((m >> 0) & 1)*16;
        int ga1 = 1*192 + k*32 + ((m >> 1) & 1)*16;
        int ga2 = 2*192 + k*32 + ((m >> 2) & 1)*16;
        int ga3 = 3*192 + k*32 + ((m >> 3) & 1)*16;
        for (int cb = 0; cb < 4; ++cb){
            int c = cb*4 + grp;
            float re = (pm == c) ? 1.f : 0.f;   // P folded into columns
            float im = 0.f;
            gate_step<0>(re, im, gtab, ga0, 0);   gate_step<1>(re, im, gtab, ga1, 0);
            gate_step<2>(re, im, gtab, ga2, 0);   gate_step<3>(re, im, gtab, ga3, 0);
            re = bperm(bpaddr, re);
            im = bperm(bpaddr, im);
            gate_step<0>(re, im, gtab, ga0, 768); gate_step<1>(re, im, gtab, ga1, 768);
            gate_step<2>(re, im, gtab, ga2, 768); gate_step<3>(re, im, gtab, ga3, 768);
            float2* dst = (float2*)&ldsf[UBo + k*512 + m*32 + c*2];
            *dst = make_float2(re, im);
        }
    }
    __syncthreads();

    // ---------------- main layout: lane = (e, s) -----------------------------
    const int e = lane & 15;       // batch element (A row, B/D col)
    const int s = lane >> 4;       // own wire / k-quarter
    const int sm1 = s & 1, sm2 = s >> 1;
    const int ecol = e & 3;

    // A-fragments of U_k (re/im) -- loaded once, pinned by the aliasing stores
    F8 are[6], aim[6];
    #pragma unroll
    for (int k = 0; k < 6; ++k){
        const float* ub = &ldsf[UBo + k*512 + e*32 + s*8];
        float4 u01 = *(const float4*)ub;         // amps 4s, 4s+1 (re,im)
        float4 u23 = *(const float4*)(ub + 4);   // amps 4s+2, 4s+3
        are[k].h[0] = (f16x2){(f16)u01.x, (f16)(-u01.y)};
        are[k].h[1] = (f16x2){(f16)u01.z, (f16)(-u01.w)};
        are[k].h[2] = (f16x2){(f16)u23.x, (f16)(-u23.y)};
        are[k].h[3] = (f16x2){(f16)u23.z, (f16)(-u23.w)};
        aim[k].h[0] = (f16x2){(f16)u01.y, (f16)u01.x};
        aim[k].h[1] = (f16x2){(f16)u01.w, (f16)u01.z};
        aim[k].h[2] = (f16x2){(f16)u23.y, (f16)u23.x};
        aim[k].h[3] = (f16x2){(f16)u23.w, (f16)u23.z};
    }
    __syncthreads();   // all lanes done reading U before anyone overwrites it

    // R8-style packed sign fragment: lane (e,s) output regs 0,1 = ev_s(even ckt), 2,3 = ev_s(odd)
    F8 asig;
    {
        int q = e >> 2;
        bool evenrows = (e & 3) < 2;
        #pragma unroll
        for (int j = 0; j < 8; ++j){
            int amp = 4*s + (j & 3);
            float v = 0.f;
            if (evenrows == (j < 4))
                v = ((amp >> q) & 1) ? -1.f : 1.f;
            asig.v[j] = (f16)v;
        }
    }
    // all-wire sign fragments: evX[j] = ev of wire j (even / odd circuit)
    F8 asigF, asigI;
    #pragma unroll
    for (int u = 0; u < 8; ++u){
        int amp = 4*s + (u & 3);
        float sg = ((amp >> ecol) & 1) ? -1.f : 1.f;
        asigF.v[u] = (f16)(u < 4 ? sg : 0.f);
        asigI.v[u] = (f16)(u >= 4 ? sg : 0.f);
    }

    // A_z (x-only): rows 4q..4q+3 all = Wd column q (k<16) -> dzx[0] = z_x(own wire)
    F8 az;
    #pragma unroll
    for (int j = 0; j < 4; ++j){
        int k0 = s*8 + 2*j, k1 = k0 + 1;
        float v0 = (k0 < 16) ? Wd[k0*20 + (e >> 2)] : 0.f;
        float v1 = (k1 < 16) ? Wd[k1*20 + (e >> 2)] : 0.f;
        az.h[j] = (f16x2){(f16)v0, (f16)v1};
    }
    const float bdv = bd[s];
    // Wd_h column s in f32: z_h,s = sum_q Wd[16+q][s] * h_q
    const float4 wqs = make_float4(Wd[16*20 + s], Wd[17*20 + s],
                                   Wd[18*20 + s], Wd[19*20 + s]);

    const int b0 = blockIdx.x * NELEM;
    const float* xp = x + (size_t)(b0 + e) * TSTEPS * NFEAT;
    // lanes s>=2 feed only k-slots >=16 where az rows are 0 -> content don't-care
    const float* xq = (s < 2) ? (xp + s*8) : xp;
    float* yp = out + (size_t)(b0 + e) * TSTEPS * 4 + s;

    const f32x4 z4 = {0.f, 0.f, 0.f, 0.f};
    float cst = 0.f;
    f32x4 hv = z4;                  // all-wire h state (f32, replicated across s)

    // x prefetch + pipelined z_x MFMA for t=0
    float4 xa = *(const float4*)(xq);
    float4 xb = *(const float4*)(xq + 4);
    F8 bz;
    bz.h[0] = pkrtz(xa.x, xa.y);
    bz.h[1] = pkrtz(xa.z, xa.w);
    bz.h[2] = pkrtz(xb.x, xb.y);
    bz.h[3] = pkrtz(xb.z, xb.w);
    f32x4 dzx = __builtin_amdgcn_mfma_f32_16x16x32_f16(az.v, bz.v, z4, 0, 0, 0);
    xa = *(const float4*)(xq + NFEAT);
    xb = *(const float4*)(xq + NFEAT + 4);

    #pragma clang loop unroll(disable)
    for (int t = 0; t < TSTEPS; ++t){
        // ---- z (own wire) = z_x (pipelined MFMA) + Wd_h^T h (f32 VALU) + bd ----
        float zval = dzx[0] + bdv
                   + wqs.x*hv[0] + wqs.y*hv[1] + wqs.z*hv[2] + wqs.w*hv[3];
        float usel = 1.f - 2.f*frcp(__expf(zval) + 1.f);
        float F0r, F0i, F1r, F1i;
        factors(usel, F0r, F0i, F1r, F1i);
        write_F(&ldsf[BCo], e, s, F0r, F0i, F1r, F1i);
        cfence();
        F8 bp;
        build_psi(&ldsf[BCo], e, sm1, sm2, bp);

        // ---- phase 1: f,i,Cg,o = 8 U-MFMAs + 2 EV-MFMAs (packed, own wire) ----
        f32x4 dre[4], dim4[4];
        #pragma unroll
        for (int k = 0; k < 4; ++k){
            dre[k]  = __builtin_amdgcn_mfma_f32_16x16x32_f16(are[k].v, bp.v, z4, 0,0,0);
            dim4[k] = __builtin_amdgcn_mfma_f32_16x16x32_f16(aim[k].v, bp.v, z4, 0,0,0);
        }
        F8 pb1 = pack_P(dre[0], dim4[0], dre[1], dim4[1]);   // f (even), i (odd)
        F8 pb2 = pack_P(dre[2], dim4[2], dre[3], dim4[3]);   // Cg, o
        f32x4 ev1 = __builtin_amdgcn_mfma_f32_16x16x32_f16(asig.v, pb1.v, z4, 0,0,0);
        f32x4 ev2 = __builtin_amdgcn_mfma_f32_16x16x32_f16(asig.v, pb2.v, z4, 0,0,0);

        // ---- pipelined z_x for t+1 ----
        if (t + 1 < TSTEPS){
            bz.h[0] = pkrtz(xa.x, xa.y);
            bz.h[1] = pkrtz(xa.z, xa.w);
            bz.h[2] = pkrtz(xb.x, xb.y);
            bz.h[3] = pkrtz(xb.z, xb.w);
            dzx = __builtin_amdgcn_mfma_f32_16x16x32_f16(az.v, bz.v, z4, 0,0,0);
            if (t + 2 < TSTEPS){
                xa = *(const float4*)(xq + (t+2)*NFEAT);
                xb = *(const float4*)(xq + (t+2)*NFEAT + 4);
            }
        }

        // ---- LSTM pointwise (own wire s only) ----
        float fg = sigm(ev1[0]), ig = sigm(ev1[2]), Cg = sigm(ev2[0]), og = sigm(ev2[2]);
        cst = fg*cst + ig*Cg;
        float rs = og * tanh_f(cst);
        factors(rs, F0r, F0i, F1r, F1i);
        write_F(&ldsf[BCo], e, s, F0r, F0i, F1r, F1i);
        cfence();
        F8 bpp;
        build_psi(&ldsf[BCo], e, sm1, sm2, bpp);

        // ---- phase 2: h (k=4), y (k=5) = 4 U-MFMAs + 2 EV-MFMAs ----
        f32x4 hre = __builtin_amdgcn_mfma_f32_16x16x32_f16(are[4].v, bpp.v, z4, 0,0,0);
        f32x4 him = __builtin_amdgcn_mfma_f32_16x16x32_f16(aim[4].v, bpp.v, z4, 0,0,0);
        f32x4 yre = __builtin_amdgcn_mfma_f32_16x16x32_f16(are[5].v, bpp.v, z4, 0,0,0);
        f32x4 yim = __builtin_amdgcn_mfma_f32_16x16x32_f16(aim[5].v, bpp.v, z4, 0,0,0);
        F8 b3 = pack_P(hre, him, yre, yim);                 // h (even), y (odd)
        hv = __builtin_amdgcn_mfma_f32_16x16x32_f16(asigF.v, b3.v, z4, 0,0,0);  // all-wire h
        f32x4 evY = __builtin_amdgcn_mfma_f32_16x16x32_f16(asigI.v, b3.v, z4, 0,0,0);

        // ---- y scatter (own wire, off critical path) ----
        yp[t*4] = sel4(evY[0], evY[1], evY[2], evY[3], s);
    }

    // final c (own wire), h (select own wire from all-wire state)
    size_t cbase = (size_t)B * TSTEPS * 4;
    out[cbase + (size_t)(b0 + e)*4 + s] = cst;
    out[cbase + (size_t)B*4 + (size_t)(b0 + e)*4 + s] = sel4(hv[0], hv[1], hv[2], hv[3], s);
}

extern "C" void kernel_launch(void* const* d_in, const int* in_sizes, int n_in,
                              void* d_out, int out_size, void* d_ws, size_t ws_size,
                              hipStream_t stream) {
    const float* x   = (const float*)d_in[0];
    const float* phi = (const float*)d_in[1];
    const float* Wd  = (const float*)d_in[2];
    const float* bd  = (const float*)d_in[3];
    float* out = (float*)d_out;
    int B = in_sizes[0] / (TSTEPS * NFEAT);   // 4096
    int blocks = B / NELEM;                   // 256 blocks x 1 wave x 16 elems
    hipLaunchKernelGGL(qlstm_kernel, dim3(blocks), dim3(64), 0, stream,
                       x, phi, Wd, bd, out, B);
}